// Round 9
// baseline (2347.963 us; speedup 1.0000x reference)
//
#include <hip/hip_runtime.h>
#include <math.h>

#define Ln 8
#define Bn 2
#define Tn 1024
#define Dm 1024
#define Hn 16
#define Fm 4096
#define Vn 50257
#define NTOK 2048   // B*T

typedef unsigned short u16;
typedef u16   u16x8  __attribute__((ext_vector_type(8)));
typedef __bf16 bf16x8 __attribute__((ext_vector_type(8)));
typedef float f32x4  __attribute__((ext_vector_type(4)));

__device__ __forceinline__ u16 f2bf(float f){
  unsigned u = __builtin_bit_cast(unsigned, f);
  u += 0x7FFFu + ((u >> 16) & 1u);            // RNE
  return (u16)(u >> 16);
}
__device__ __forceinline__ float bf2f(u16 s){
  return __builtin_bit_cast(float, ((unsigned)s) << 16);
}
__device__ __forceinline__ float gelu_f(float v){
  return 0.5f * v * (1.0f + erff(v * 0.70710678118654752440f));
}
__device__ __forceinline__ void gload16(const void* g, void* l){
  __builtin_amdgcn_global_load_lds(
      (const __attribute__((address_space(1))) void*)g,
      (__attribute__((address_space(3))) void*)l, 16, 0, 0);
}

// ---------------- embedding ----------------
__global__ __launch_bounds__(256) void embed_kernel(const int* __restrict__ idx,
                                                    const float* __restrict__ emb,
                                                    const float* __restrict__ pos,
                                                    float* __restrict__ x){
  int row = blockIdx.x;
  int t = row & (Tn - 1);
  int id = idx[row];
  const float4* e = (const float4*)(emb + (size_t)id * Dm);
  const float4* p = (const float4*)(pos + (size_t)t * Dm);
  float4* o = (float4*)(x + (size_t)row * Dm);
  int i = threadIdx.x;
  float4 a = e[i], b = p[i];
  o[i] = make_float4(a.x + b.x, a.y + b.y, a.z + b.z, a.w + b.w);
}

// ---------------- LN row stats: mean + rstd per row ----------------
__global__ __launch_bounds__(256) void ln_stats(const float* __restrict__ xin,
                                                float2* __restrict__ st){
  int row = blockIdx.x * 4 + (threadIdx.x >> 6);
  int lane = threadIdx.x & 63;
  const float4* xr = (const float4*)(xin + (size_t)row * Dm);
  float s = 0.0f, s2 = 0.0f;
  #pragma unroll
  for (int i = 0; i < 4; i++){
    float4 v = xr[lane + i * 64];
    s  += v.x + v.y + v.z + v.w;
    s2 += v.x*v.x + v.y*v.y + v.z*v.z + v.w*v.w;
  }
  #pragma unroll
  for (int off = 1; off < 64; off <<= 1){
    s  += __shfl_xor(s, off);
    s2 += __shfl_xor(s2, off);
  }
  if (lane == 0){
    float mean = s * (1.0f / Dm);
    float var  = s2 * (1.0f / Dm) - mean * mean;
    st[row] = make_float2(mean, rsqrtf(var + 1e-5f));
  }
}

// ---------------- layernorm (f32 in, bf16 out) — final LN only ----------------
__global__ __launch_bounds__(256) void ln_kernel(const float* __restrict__ xin,
                                                 const float* __restrict__ w,
                                                 const float* __restrict__ bb,
                                                 u16* __restrict__ out){
  int row = blockIdx.x;
  int t = threadIdx.x;
  float4 v = ((const float4*)(xin + (size_t)row * Dm))[t];
  float s  = v.x + v.y + v.z + v.w;
  float s2 = v.x*v.x + v.y*v.y + v.z*v.z + v.w*v.w;
  #pragma unroll
  for (int off = 1; off < 64; off <<= 1){
    s  += __shfl_xor(s, off);
    s2 += __shfl_xor(s2, off);
  }
  __shared__ float red[8];
  int wv = t >> 6, lane = t & 63;
  if (lane == 0){ red[wv] = s; red[4 + wv] = s2; }
  __syncthreads();
  s  = red[0] + red[1] + red[2] + red[3];
  s2 = red[4] + red[5] + red[6] + red[7];
  float mean = s * (1.0f / Dm);
  float var  = s2 * (1.0f / Dm) - mean * mean;
  float rs = rsqrtf(var + 1e-5f);
  float4 wv4 = ((const float4*)w)[t];
  float4 bv4 = ((const float4*)bb)[t];
  u16 o4[4];
  o4[0] = f2bf((v.x - mean) * rs * wv4.x + bv4.x);
  o4[1] = f2bf((v.y - mean) * rs * wv4.y + bv4.y);
  o4[2] = f2bf((v.z - mean) * rs * wv4.z + bv4.z);
  o4[3] = f2bf((v.w - mean) * rs * wv4.w + bv4.w);
  *(uint2*)(out + (size_t)row * Dm + t * 4) = *(uint2*)o4;
}

// ---------------- transpose tile: f32 src[k][srcCol+*] -> bf16 dst[dstRow+*][k] ----------------
__device__ __forceinline__ void trans_tile(const float* __restrict__ src,
                                           u16* __restrict__ dst,
                                           int N, int K, int srcCol, int dstRow, int k0){
  __shared__ float tile[64][66];
  int t = threadIdx.x;
  int rr = t >> 4, nc = (t & 15) * 4;
  #pragma unroll
  for (int u = 0; u < 4; u++){
    int kk = rr + u * 16;
    int gn = srcCol + nc;
    const float* sp = src + (size_t)(k0 + kk) * N;
    float4 v;
    if (gn + 3 < N) v = *(const float4*)(sp + gn);
    else {
      v.x = (gn     < N) ? sp[gn]     : 0.0f;
      v.y = (gn + 1 < N) ? sp[gn + 1] : 0.0f;
      v.z = (gn + 2 < N) ? sp[gn + 2] : 0.0f;
      v.w = (gn + 3 < N) ? sp[gn + 3] : 0.0f;
    }
    tile[kk][nc]     = v.x;
    tile[kk][nc + 1] = v.y;
    tile[kk][nc + 2] = v.z;
    tile[kk][nc + 3] = v.w;
  }
  __syncthreads();
  int np = t >> 2, c = t & 3;
  u16* dp = dst + (size_t)(dstRow + np) * K + k0;
  u16 pk[8];
  #pragma unroll
  for (int j = 0; j < 8; j++) pk[j] = f2bf(tile[c*8 + j][np]);
  *(int4*)(dp + c*8) = *(int4*)pk;
  #pragma unroll
  for (int j = 0; j < 8; j++) pk[j] = f2bf(tile[32 + c*8 + j][np]);
  *(int4*)(dp + 32 + c*8) = *(int4*)pk;
}

__global__ __launch_bounds__(256) void transpose_w(const float* __restrict__ Bw,
                                                   u16* __restrict__ Bt,
                                                   int N, int K, int c0){
  int n0 = blockIdx.x * 64, k0 = blockIdx.y * 64;
  trans_tile(Bw, Bt, N, K, c0 + n0, n0, k0);
}

// all layer weights + head in ONE dispatch.
__global__ __launch_bounds__(256) void mega_transpose(const float* __restrict__ qkvw,
                                                      const float* __restrict__ fc1w,
                                                      const float* __restrict__ fc2w,
                                                      const float* __restrict__ headw,
                                                      u16* __restrict__ Wq,
                                                      u16* __restrict__ W1,
                                                      u16* __restrict__ W2,
                                                      u16* __restrict__ Wh){
  int id = blockIdx.x;
  const float* src; u16* dst; int N, K, n0, k0;
  if (id < 6144){
    int l = id / 768, r = id % 768;
    n0 = (r % 48) * 64; k0 = (r / 48) * 64;
    src = qkvw + (size_t)l * Dm * 3072; dst = Wq + (size_t)l * 3072 * Dm;
    N = 3072; K = Dm;
  } else if (id < 14336){
    int id2 = id - 6144;
    int l = id2 / 1024, r = id2 % 1024;
    n0 = (r % 64) * 64; k0 = (r / 64) * 64;
    src = fc1w + (size_t)l * Dm * Fm; dst = W1 + (size_t)l * Fm * Dm;
    N = Fm; K = Dm;
  } else if (id < 22528){
    int id2 = id - 14336;
    int l = id2 / 1024, r = id2 % 1024;
    n0 = (r % 16) * 64; k0 = (r / 16) * 64;
    src = fc2w + (size_t)l * Fm * Dm; dst = W2 + (size_t)l * Dm * Fm;
    N = Dm; K = Fm;
  } else {
    int id2 = id - 22528;
    n0 = (id2 % 788) * 64; k0 = (id2 / 788) * 64;   // 50432 rows, zero-filled past 50257
    src = headw; dst = Wh;
    N = Vn; K = Dm;
  }
  trans_tile(src, dst, N, K, n0, n0, k0);
}

// ---------------- generic 2-phase GEMM ----------------
// FUSE: A comes from f32 x with LN applied in reg-staging (write-side swizzle mirror).
template<int MODE, int BMt, int BNt, int WM, int WN, bool SWZ, bool FUSE>
__global__ __launch_bounds__(256) void gemm_kernel(const u16* __restrict__ A,
                                                   const u16* __restrict__ Bt,
                                                   const float* __restrict__ bias,
                                                   void* __restrict__ outp,
                                                   float* __restrict__ resid,
                                                   u16* __restrict__ vT,
                                                   const float* __restrict__ xin,
                                                   const float2* __restrict__ stats,
                                                   const float* __restrict__ lnw,
                                                   const float* __restrict__ lnb,
                                                   int K, int Nout, int c0){
  constexpr int MR = BMt / (WM * 16);
  constexpr int NR = BNt / (WN * 16);
  constexpr int TPR = 256 / BMt;           // FUSE: threads per A row
  constexpr int CPT = 64 / TPR;            // FUSE: f32 cols per thread per K-step
  __shared__ u16 sA[BMt][64];
  __shared__ u16 sB[BNt][64];
  int t = threadIdx.x;
  int lane = t & 63, w = t >> 6;
  int wm = w / WN, wn = w % WN;
  int lr = lane & 15, lg = lane >> 4;
  int m0, n0;
  if (SWZ){
    int orig = blockIdx.x;
    int q = gridDim.x >> 3;
    int wg = (orig & 7) * q + (orig >> 3);
    m0 = (wg & 15) * BMt;
    n0 = (wg >> 4) * BNt;
  } else {
    m0 = blockIdx.y * BMt; n0 = blockIdx.x * BNt;
  }

  f32x4 acc[MR][NR] = {};

  int srow = lane >> 3;
  int gcs = ((lane & 7) ^ (lane >> 3)) * 8;        // pre-swizzled global k-col (u16)
  int cswz = (lr & 7) << 3;                        // read-side swizzle

  // FUSE staging coords
  int frow = t / TPR;
  int fcl  = (t % TPR) * CPT;
  float2 mr = FUSE ? stats[m0 + frow] : make_float2(0.f, 0.f);
  const float* xrow = FUSE ? (xin + (size_t)(m0 + frow) * 1024 + fcl) : nullptr;

  for (int k0 = 0; k0 < K; k0 += 64){
    __syncthreads();
    if (FUSE){
      u16 pk[CPT];
      #pragma unroll
      for (int ci = 0; ci < CPT; ci += 4){
        float4 v  = *(const float4*)(xrow + k0 + ci);
        float4 wv = *(const float4*)(lnw + k0 + fcl + ci);
        float4 bv = *(const float4*)(lnb + k0 + fcl + ci);
        pk[ci+0] = f2bf((v.x - mr.x) * mr.y * wv.x + bv.x);
        pk[ci+1] = f2bf((v.y - mr.x) * mr.y * wv.y + bv.y);
        pk[ci+2] = f2bf((v.z - mr.x) * mr.y * wv.z + bv.z);
        pk[ci+3] = f2bf((v.w - mr.x) * mr.y * wv.w + bv.w);
      }
      int s0 = fcl >> 3;                            // 16B slot index
      #pragma unroll
      for (int sj = 0; sj < CPT/8; sj++)
        *(int4*)&sA[frow][((s0 + sj) ^ (frow & 7)) * 8] = *(int4*)&pk[sj*8];
    } else {
      #pragma unroll
      for (int i = 0; i < BMt/32; i++){
        int rbase = i*32 + w*8;
        gload16(A + (size_t)(m0 + rbase + srow) * K + k0 + gcs, (char*)&sA[rbase][0]);
      }
    }
    #pragma unroll
    for (int i = 0; i < BNt/32; i++){
      int rbase = i*32 + w*8;
      gload16(Bt + (size_t)(n0 + rbase + srow) * K + k0 + gcs, (char*)&sB[rbase][0]);
    }
    __syncthreads();
    #pragma unroll
    for (int kk = 0; kk < 2; kk++){
      bf16x8 af[MR], bfr[NR];
      #pragma unroll
      for (int i = 0; i < MR; i++) af[i]  = *(const bf16x8*)&sA[wm*(MR*16) + i*16 + lr][(kk*32 + lg*8) ^ cswz];
      #pragma unroll
      for (int j = 0; j < NR; j++) bfr[j] = *(const bf16x8*)&sB[wn*(NR*16) + j*16 + lr][(kk*32 + lg*8) ^ cswz];
      #pragma unroll
      for (int i = 0; i < MR; i++)
        #pragma unroll
        for (int j = 0; j < NR; j++)
          acc[i][j] = __builtin_amdgcn_mfma_f32_16x16x32_bf16(af[i], bfr[j], acc[i][j], 0, 0, 0);
    }
  }

  #pragma unroll
  for (int i = 0; i < MR; i++){
    int gr0 = m0 + wm*(MR*16) + i*16 + lg*4;
    #pragma unroll
    for (int j = 0; j < NR; j++){
      int gc = c0 + n0 + wn*(NR*16) + j*16 + lr;
      if (MODE == 3 && gc >= Nout) continue;
      float bb = bias[gc];
      if (MODE == 0 && gc >= 2048){
        int hh = (gc - 2048) >> 6, dd = (gc - 2048) & 63;
        int b_ = gr0 >> 10, tt = gr0 & 1023;
        u16 pk[4];
        #pragma unroll
        for (int r = 0; r < 4; r++) pk[r] = f2bf(acc[i][j][r] + bb);
        *(uint2*)&vT[((size_t)((b_*Hn + hh)*64 + dd))*Tn + tt] = *(uint2*)pk;
        continue;
      }
      #pragma unroll
      for (int r = 0; r < 4; r++){
        float v = acc[i][j][r] + bb;
        size_t oi = (size_t)(gr0 + r) * Nout + gc;
        if (MODE == 0)      ((u16*)outp)[oi] = f2bf(v);
        else if (MODE == 1) ((u16*)outp)[oi] = f2bf(gelu_f(v));
        else if (MODE == 2) resid[oi] = resid[oi] + gelu_f(v);
        else                ((float*)outp)[oi] = v;
      }
    }
  }
}

// ---------------- 8-phase 256x256 head GEMM (r6 version — best measured) ----------------
#define BARR() __builtin_amdgcn_s_barrier()
#define LGK0() asm volatile("s_waitcnt lgkmcnt(0)" ::: "memory")
#define VMC4() asm volatile("s_waitcnt vmcnt(4)" ::: "memory")

__global__ __launch_bounds__(512) void head_gemm_8ph(const u16* __restrict__ A,
                                                     const u16* __restrict__ Bw,
                                                     const float* __restrict__ bias,
                                                     float* __restrict__ out){
  __shared__ u16 sA[2][256][64];
  __shared__ u16 sB[2][256][64];
  int t = threadIdx.x, lane = t & 63, w = t >> 6;
  int wm = w >> 2, wn = w & 3;
  int lr = lane & 15, lg = lane >> 4;
  int orig = blockIdx.x;
  int wg = (orig & 7) * (gridDim.x >> 3) + (orig >> 3);  // XCD-chunked (1576 % 8 == 0)
  int m0g = (wg & 7) << 8;                                // m-fastest: B-panel reuse in-XCD
  int n0g = (wg >> 3) << 8;

  int srow = w*8 + (lane >> 3);
  int scol = ((lane & 7) ^ (lane >> 3)) * 8;     // pre-swizzled source col (u16)
  const u16* Abase = A  + (size_t)(m0g + srow) * 1024 + scol;
  const u16* Bbase = Bw + (size_t)(n0g + srow) * 1024 + scol;

  f32x4 acc[8][4] = {};
  bf16x8 a[4][2], b0[2][2], b1[2][2];
  int rsw = (lr & 7) << 3;

  auto stA = [&](int buf, int half, int tile){
    const u16* s = Abase + (size_t)half*128*1024 + tile*64;
    gload16(s,           &sA[buf][half*128 +      w*8][0]);
    gload16(s + 64*1024, &sA[buf][half*128 + 64 + w*8][0]);
  };
  auto stB = [&](int buf, int half, int tile){
    const u16* s = Bbase + (size_t)half*128*1024 + tile*64;
    gload16(s,           &sB[buf][half*128 +      w*8][0]);
    gload16(s + 64*1024, &sB[buf][half*128 + 64 + w*8][0]);
  };
  auto rdA = [&](int buf, int half){
    #pragma unroll
    for (int i = 0; i < 4; i++)
      #pragma unroll
      for (int kk = 0; kk < 2; kk++)
        a[i][kk] = *(const bf16x8*)&sA[buf][wm*128 + half*64 + i*16 + lr][(kk*32 + lg*8) ^ rsw];
  };
  auto rdB = [&](int buf, int half, bf16x8 (&bb)[2][2]){
    #pragma unroll
    for (int j = 0; j < 2; j++)
      #pragma unroll
      for (int kk = 0; kk < 2; kk++)
        bb[j][kk] = *(const bf16x8*)&sB[buf][wn*64 + half*32 + j*16 + lr][(kk*32 + lg*8) ^ rsw];
  };
  auto MF = [&](int mb, int nb, bf16x8 (&bb)[2][2]){
    __builtin_amdgcn_s_setprio(1);
    #pragma unroll
    for (int kk = 0; kk < 2; kk++)
      #pragma unroll
      for (int i = 0; i < 4; i++)
        #pragma unroll
        for (int j = 0; j < 2; j++)
          acc[mb+i][nb+j] = __builtin_amdgcn_mfma_f32_16x16x32_bf16(a[i][kk], bb[j][kk], acc[mb+i][nb+j], 0, 0, 0);
    __builtin_amdgcn_s_setprio(0);
  };

  // prologue: tile0 full + tile1 B-halves; wait tile0 landed (allow t1.B in flight)
  stA(0,0,0); stA(0,1,0); stB(0,0,0); stB(0,1,0);
  stB(1,0,1); stB(1,1,1);
  VMC4();
  BARR();

  for (int it = 0; it < 8; ++it){
    int T = it * 2;
    // ---- tile T (buf0) ----
    rdA(0,0); rdB(0,0,b0);                 // P1
    stA(1,0,T+1);
    BARR(); LGK0(); MF(0,0,b0); BARR();
    rdB(0,1,b1);                           // P2
    stA(1,1,T+1);
    BARR(); LGK0(); MF(0,2,b1); BARR();
    rdA(0,1);                              // P3
    if (T+2 < 16) stB(0,0,T+2);
    BARR(); LGK0(); MF(4,2,b1); BARR();
    if (T+2 < 16) stB(0,1,T+2);            // P4
    BARR(); MF(4,0,b0); VMC4(); BARR();
    // ---- tile T+1 (buf1) ----
    rdA(1,0); rdB(1,0,b0);                 // P5
    if (T+2 < 16) stA(0,0,T+2);
    BARR(); LGK0(); MF(0,0,b0); BARR();
    rdB(1,1,b1);                           // P6
    if (T+2 < 16) stA(0,1,T+2);
    BARR(); LGK0(); MF(0,2,b1); BARR();
    rdA(1,1);                              // P7
    if (T+3 < 16) stB(1,0,T+3);
    BARR(); LGK0(); MF(4,2,b1); BARR();
    if (T+3 < 16) stB(1,1,T+3);            // P8
    BARR(); MF(4,0,b0); VMC4(); BARR();
  }

  #pragma unroll
  for (int m = 0; m < 8; m++){
    int gr = m0g + wm*128 + m*16 + lg*4;
    #pragma unroll
    for (int n = 0; n < 4; n++){
      int gc = n0g + wn*64 + n*16 + lr;
      if (gc < Vn){
        float bb = bias[gc];
        #pragma unroll
        for (int r = 0; r < 4; r++)
          out[(size_t)(gr + r) * Vn + gc] = acc[m][n][r] + bb;
      }
    }
  }
}

// ---------------- MFMA fused causal attention (dbuf K/V, T14 staging, T13 defer-max) ----------------
__global__ __launch_bounds__(256) void attn_mfma(const u16* __restrict__ qkv,
                                                 const u16* __restrict__ vT,
                                                 float* __restrict__ x){
  int bid = blockIdx.x;
  int bh = bid & 31;
  int j = bid >> 5;
  int qt = (j < 8) ? (15 - j) : (j - 8);
  int b = bh >> 4, h_ = bh & 15;
  int t = threadIdx.x;
  int w = t >> 6, lane = t & 63;
  int lr = lane & 15, lg = lane >> 4;

  __shared__ u16 sK [2][64][72];
  __shared__ u16 sVt[2][64][72];
  __shared__ u16 sP [64][72];

  const u16* qbase = qkv + ((size_t)(b*Tn + qt*64 + w*16 + lr)) * 3*Dm + h_*64 + lg*8;
  bf16x8 qf[2];
  #pragma unroll
  for (int i = 0; i < 2; i++){
    u16x8 raw = *(const u16x8*)(qbase + i * 32);
    #pragma unroll
    for (int u = 0; u < 8; u++) qf[i][u] = (__bf16)(bf2f(raw[u]) * 0.03125f);
  }

  f32x4 o_[4] = {};
  float m_[4], l_[4];
  #pragma unroll
  for (int r = 0; r < 4; r++){ m_[r] = -INFINITY; l_[r] = 0.0f; }

  int sr = t >> 2, scc = (t & 3) * 16;
  const u16* kbase = qkv + ((size_t)(b*Tn + sr)) * 3*Dm + Dm + h_*64 + scc;
  const u16* vbase = vT + ((size_t)(bh*64 + sr)) * Tn + scc;
  int4 kr0, kr1, vr0, vr1;

  kr0 = *(const int4*)(kbase);     kr1 = *(const int4*)(kbase + 8);
  vr0 = *(const int4*)(vbase);     vr1 = *(const int4*)(vbase + 8);
  *(int4*)&sK [0][sr][scc]     = kr0;  *(int4*)&sK [0][sr][scc + 8] = kr1;
  *(int4*)&sVt[0][sr][scc]     = vr0;  *(int4*)&sVt[0][sr][scc + 8] = vr1;

  for (int kt = 0; kt <= qt; kt++){
    int cur = kt & 1;
    if (kt < qt){                  // T14: issue next tile's loads before compute
      const u16* kb = kbase + (size_t)(kt + 1) * 64 * 3 * Dm;
      const u16* vb = vbase + (kt + 1) * 64;
      kr0 = *(const int4*)(kb);    kr1 = *(const int4*)(kb + 8);
      vr0 = *(const int4*)(vb);    vr1 = *(const int4*)(vb + 8);
    }
    __syncthreads();

    f32x4 s[4] = {};
    __builtin_amdgcn_s_setprio(1);
    #pragma unroll
    for (int kf = 0; kf < 2; kf++){
      #pragma unroll
      for (int nf = 0; nf < 4; nf++){
        bf16x8 kfrag = *(const bf16x8*)&sK[cur][nf*16 + lr][kf*32 + lg*8];
        s[nf] = __builtin_amdgcn_mfma_f32_16x16x32_bf16(qf[kf], kfrag, s[nf], 0, 0, 0);
      }
    }
    __builtin_amdgcn_s_setprio(0);

    bool lastt = (kt == qt);
    float tmax[4] = {-INFINITY, -INFINITY, -INFINITY, -INFINITY};
    #pragma unroll
    for (int nf = 0; nf < 4; nf++)
      #pragma unroll
      for (int r = 0; r < 4; r++){
        float v = s[nf][r];
        if (lastt){
          int kkg = nf*16 + lr, qg = w*16 + lg*4 + r;
          if (kkg > qg) v = -INFINITY;
        }
        s[nf][r] = v;
        tmax[r] = fmaxf(tmax[r], v);
      }
    #pragma unroll
    for (int r = 0; r < 4; r++){
      tmax[r] = fmaxf(tmax[r], __shfl_xor(tmax[r], 1));
      tmax[r] = fmaxf(tmax[r], __shfl_xor(tmax[r], 2));
      tmax[r] = fmaxf(tmax[r], __shfl_xor(tmax[r], 4));
      tmax[r] = fmaxf(tmax[r], __shfl_xor(tmax[r], 8));
    }
    // T13 defer-max: skip rescale while per-row growth <= 8 (P bounded by e^8, f32-safe)
    bool need = false;
    #pragma unroll
    for (int r = 0; r < 4; r++) need = need || (tmax[r] > m_[r] + 8.0f);
    if (__any(need)){
      #pragma unroll
      for (int r = 0; r < 4; r++){
        float nm = fmaxf(m_[r], tmax[r]);
        float resc = __expf(m_[r] - nm);
        m_[r] = nm;
        l_[r] *= resc;
        #pragma unroll
        for (int df = 0; df < 4; df++) o_[df][r] *= resc;
      }
    }
    float psum[4] = {0.f, 0.f, 0.f, 0.f};
    #pragma unroll
    for (int nf = 0; nf < 4; nf++)
      #pragma unroll
      for (int r = 0; r < 4; r++){
        float pv = __expf(s[nf][r] - m_[r]);
        s[nf][r] = pv;
        psum[r] += pv;
      }
    #pragma unroll
    for (int r = 0; r < 4; r++){
      psum[r] += __shfl_xor(psum[r], 1);
      psum[r] += __shfl_xor(psum[r], 2);
      psum[r] += __shfl_xor(psum[r], 4);
      psum[r] += __shfl_xor(psum[r], 8);
      l_[r] += psum[r];
    }

    #pragma unroll
    for (int nf = 0; nf < 4; nf++)
      #pragma unroll
      for (int r = 0; r < 4; r++)
        sP[w*16 + lg*4 + r][nf*16 + lr] = f2bf(s[nf][r]);

    __builtin_amdgcn_s_setprio(1);
    #pragma unroll
    for (int kf = 0; kf < 2; kf++){
      bf16x8 pfrag = *(const bf16x8*)&sP[w*16 + lr][kf*32 + lg*8];
      #pragma unroll
      for (int df = 0; df < 4; df++){
        bf16x8 vfrag = *(const bf16x8*)&sVt[cur][df*16 + lr][kf*32 + lg*8];
        o_[df] = __builtin_amdgcn_mfma_f32_16x16x32_bf16(pfrag, vfrag, o_[df], 0, 0, 0);
      }
    }
    __builtin_amdgcn_s_setprio(0);

    if (kt < qt){                  // write-late: land next tile in the other buffer
      int nxt = cur ^ 1;
      *(int4*)&sK [nxt][sr][scc]     = kr0;  *(int4*)&sK [nxt][sr][scc + 8] = kr1;
      *(int4*)&sVt[nxt][sr][scc]     = vr0;  *(int4*)&sVt[nxt][sr][scc + 8] = vr1;
    }
  }

  float inv[4];
  #pragma unroll
  for (int r = 0; r < 4; r++) inv[r] = 1.0f / l_[r];
  #pragma unroll
  for (int df = 0; df < 4; df++)
    #pragma unroll
    for (int r = 0; r < 4; r++){
      float* xr = x + ((size_t)(b*Tn + qt*64 + w*16 + lg*4 + r)) * Dm + h_*64 + df*16 + lr;
      *xr += o_[df][r] * inv[r];
    }
}

// ---------------- host orchestration ----------------
extern "C" void kernel_launch(void* const* d_in, const int* in_sizes, int n_in,
                              void* d_out, int out_size, void* d_ws, size_t ws_size,
                              hipStream_t stream){
  const int*   idx   = (const int*)  d_in[0];
  const float* emb   = (const float*)d_in[1];
  const float* pos   = (const float*)d_in[2];
  const float* ln1w  = (const float*)d_in[3];
  const float* ln1b  = (const float*)d_in[4];
  const float* qkvw  = (const float*)d_in[5];
  const float* qkvb  = (const float*)d_in[6];
  const float* ln2w  = (const float*)d_in[7];
  const float* ln2b  = (const float*)d_in[8];
  const float* fc1w  = (const float*)d_in[9];
  const float* fc1b  = (const float*)d_in[10];
  const float* fc2w  = (const float*)d_in[11];
  const float* fc2b  = (const float*)d_in[12];
  const float* lnfw  = (const float*)d_in[13];
  const float* lnfb  = (const float*)d_in[14];
  const float* headw = (const float*)d_in[15];
  const float* headb = (const float*)d_in[16];
  float* out = (float*)d_out;

  const size_t MB = 1u << 20;
  char* ws = (char*)d_ws;
  float*  x     = (float*)(ws);                    // 8 MB  [2048][1024] f32
  u16*    h     = (u16*)  (ws + 8*MB);             // 4 MB  [2048][1024] bf16 (final LN only)
  u16*    qkv   = (u16*)  (ws + 12*MB);            // 12 MB [2048][3072] bf16
  u16*    f1    = (u16*)  (ws + 24*MB);            // 16 MB [2048][4096] bf16
  float2* stats = (float2*)(ws + 40*MB);           // 16 KB [2048] (mean, rstd)

  bool mega    = ws_size >= 320*MB;
  bool bighead = ws_size >= 116*MB;

  u16 *vT, *Bt = nullptr, *BtF = nullptr, *Wq = nullptr, *W1 = nullptr, *W2 = nullptr, *Wh = nullptr;
  if (mega){
    vT = (u16*)(ws + 41*MB);                       // 4 MB
    Wq = (u16*)(ws + 45*MB);                       // 48 MB  (8 x 3072x1024)
    W1 = (u16*)(ws + 93*MB);                       // 64 MB  (8 x 4096x1024)
    W2 = (u16*)(ws + 157*MB);                      // 64 MB  (8 x 1024x4096)
    Wh = (u16*)(ws + 221*MB);                      // 98.5 MiB (50432x1024)
  } else {
    Bt  = (u16*)(ws + 41*MB);
    vT  = (u16*)(ws + 49*MB);
    BtF = (u16*)(ws + 12*MB);
  }

  if (mega)
    mega_transpose<<<35136, 256, 0, stream>>>(qkvw, fc1w, fc2w, headw, Wq, W1, W2, Wh);

  embed_kernel<<<NTOK, 256, 0, stream>>>(idx, emb, pos, x);

  for (int l = 0; l < Ln; l++){
    const u16* Bq = mega ? Wq + (size_t)l*3072*Dm : Bt;
    const u16* B1 = mega ? W1 + (size_t)l*Fm*Dm   : Bt;
    const u16* B2 = mega ? W2 + (size_t)l*Dm*Fm   : Bt;
    // --- attention block ---
    ln_stats<<<NTOK/4, 256, 0, stream>>>(x, stats);
    if (!mega) transpose_w<<<dim3(3072/64, Dm/64), 256, 0, stream>>>(qkvw + (size_t)l*Dm*3072, Bt, 3072, Dm, 0);
    gemm_kernel<0, 64,128,1,4,false,true><<<dim3(3072/128, NTOK/64), 256, 0, stream>>>(
        nullptr, Bq, qkvb + l*3072, qkv, nullptr, vT, x, stats, ln1w + l*Dm, ln1b + l*Dm, Dm, 3072, 0);
    attn_mfma<<<512, 256, 0, stream>>>(qkv, vT, x);
    // --- MLP block ---
    ln_stats<<<NTOK/4, 256, 0, stream>>>(x, stats);
    if (!mega) transpose_w<<<dim3(Fm/64, Dm/64), 256, 0, stream>>>(fc1w + (size_t)l*Dm*Fm, Bt, Fm, Dm, 0);
    gemm_kernel<1,128,128,2,2,false,true><<<dim3(Fm/128, NTOK/128), 256, 0, stream>>>(
        nullptr, B1, fc1b + l*Fm, f1, nullptr, nullptr, x, stats, ln2w + l*Dm, ln2b + l*Dm, Dm, Fm, 0);
    if (!mega) transpose_w<<<dim3(Dm/64, Fm/64), 256, 0, stream>>>(fc2w + (size_t)l*Fm*Dm, Bt, Dm, Fm, 0);
    gemm_kernel<2, 64,64,2,2,false,false><<<dim3(Dm/64, NTOK/64), 256, 0, stream>>>(
        f1, B2, fc2b + l*Dm, nullptr, x, nullptr, nullptr, nullptr, nullptr, nullptr, Fm, Dm, 0);
  }

  ln_kernel<<<NTOK, 256, 0, stream>>>(x, lnfw, lnfb, h);

  if (mega){
    head_gemm_8ph<<<1576, 512, 0, stream>>>(h, Wh, headb, out);    // 8 m x 197 n tiles
  } else if (bighead){
    transpose_w<<<dim3(786, Dm/64), 256, 0, stream>>>(headw, BtF, Vn, Dm, 0);
    gemm_kernel<3,128,128,2,2,true,false><<<6288, 256, 0, stream>>>(
        h, BtF, headb, out, nullptr, nullptr, nullptr, nullptr, nullptr, nullptr, Dm, Vn, 0);
  } else {
    const int CHUNK = 4096;
    for (int c0 = 0; c0 < Vn; c0 += CHUNK){
      int W = Vn - c0; if (W > CHUNK) W = CHUNK;
      int ngx = (W + 127) / 128;
      transpose_w<<<dim3(ngx * 2, Dm/64), 256, 0, stream>>>(headw, Bt, Vn, Dm, c0);
      gemm_kernel<3,128,128,2,2,false,false><<<dim3(ngx, NTOK/128), 256, 0, stream>>>(
          h, Bt, headb, out, nullptr, nullptr, nullptr, nullptr, nullptr, nullptr, Dm, Vn, c0);
    }
  }
}

// Round 10
// 1803.044 us; speedup vs baseline: 1.3022x; 1.3022x over previous
//
#include <hip/hip_runtime.h>
#include <math.h>

#define Ln 8
#define Bn 2
#define Tn 1024
#define Dm 1024
#define Hn 16
#define Fm 4096
#define Vn 50257
#define NTOK 2048   // B*T

typedef unsigned short u16;
typedef u16   u16x8  __attribute__((ext_vector_type(8)));
typedef __bf16 bf16x8 __attribute__((ext_vector_type(8)));
typedef float f32x4  __attribute__((ext_vector_type(4)));

__device__ __forceinline__ u16 f2bf(float f){
  unsigned u = __builtin_bit_cast(unsigned, f);
  u += 0x7FFFu + ((u >> 16) & 1u);            // RNE
  return (u16)(u >> 16);
}
__device__ __forceinline__ float bf2f(u16 s){
  return __builtin_bit_cast(float, ((unsigned)s) << 16);
}
__device__ __forceinline__ float gelu_f(float v){
  return 0.5f * v * (1.0f + erff(v * 0.70710678118654752440f));
}
__device__ __forceinline__ void gload16(const void* g, void* l){
  __builtin_amdgcn_global_load_lds(
      (const __attribute__((address_space(1))) void*)g,
      (__attribute__((address_space(3))) void*)l, 16, 0, 0);
}

// ---------------- embedding ----------------
__global__ __launch_bounds__(256) void embed_kernel(const int* __restrict__ idx,
                                                    const float* __restrict__ emb,
                                                    const float* __restrict__ pos,
                                                    float* __restrict__ x){
  int row = blockIdx.x;
  int t = row & (Tn - 1);
  int id = idx[row];
  const float4* e = (const float4*)(emb + (size_t)id * Dm);
  const float4* p = (const float4*)(pos + (size_t)t * Dm);
  float4* o = (float4*)(x + (size_t)row * Dm);
  int i = threadIdx.x;
  float4 a = e[i], b = p[i];
  o[i] = make_float4(a.x + b.x, a.y + b.y, a.z + b.z, a.w + b.w);
}

// ---------------- layernorm (f32 in, bf16 out) ----------------
__global__ __launch_bounds__(256) void ln_kernel(const float* __restrict__ xin,
                                                 const float* __restrict__ w,
                                                 const float* __restrict__ bb,
                                                 u16* __restrict__ out){
  int row = blockIdx.x;
  int t = threadIdx.x;
  float4 v = ((const float4*)(xin + (size_t)row * Dm))[t];
  float s  = v.x + v.y + v.z + v.w;
  float s2 = v.x*v.x + v.y*v.y + v.z*v.z + v.w*v.w;
  #pragma unroll
  for (int off = 1; off < 64; off <<= 1){
    s  += __shfl_xor(s, off);
    s2 += __shfl_xor(s2, off);
  }
  __shared__ float red[8];
  int wv = t >> 6, lane = t & 63;
  if (lane == 0){ red[wv] = s; red[4 + wv] = s2; }
  __syncthreads();
  s  = red[0] + red[1] + red[2] + red[3];
  s2 = red[4] + red[5] + red[6] + red[7];
  float mean = s * (1.0f / Dm);
  float var  = s2 * (1.0f / Dm) - mean * mean;
  float rs = rsqrtf(var + 1e-5f);
  float4 wv4 = ((const float4*)w)[t];
  float4 bv4 = ((const float4*)bb)[t];
  u16 o4[4];
  o4[0] = f2bf((v.x - mean) * rs * wv4.x + bv4.x);
  o4[1] = f2bf((v.y - mean) * rs * wv4.y + bv4.y);
  o4[2] = f2bf((v.z - mean) * rs * wv4.z + bv4.z);
  o4[3] = f2bf((v.w - mean) * rs * wv4.w + bv4.w);
  *(uint2*)(out + (size_t)row * Dm + t * 4) = *(uint2*)o4;
}

// ---------------- transpose tile: f32 src[k][srcCol+*] -> bf16 dst[dstRow+*][k] ----------------
__device__ __forceinline__ void trans_tile(const float* __restrict__ src,
                                           u16* __restrict__ dst,
                                           int N, int K, int srcCol, int dstRow, int k0){
  __shared__ float tile[64][66];
  int t = threadIdx.x;
  int rr = t >> 4, nc = (t & 15) * 4;
  #pragma unroll
  for (int u = 0; u < 4; u++){
    int kk = rr + u * 16;
    int gn = srcCol + nc;
    const float* sp = src + (size_t)(k0 + kk) * N;
    float4 v;
    if (gn + 3 < N) v = *(const float4*)(sp + gn);
    else {
      v.x = (gn     < N) ? sp[gn]     : 0.0f;
      v.y = (gn + 1 < N) ? sp[gn + 1] : 0.0f;
      v.z = (gn + 2 < N) ? sp[gn + 2] : 0.0f;
      v.w = (gn + 3 < N) ? sp[gn + 3] : 0.0f;
    }
    tile[kk][nc]     = v.x;
    tile[kk][nc + 1] = v.y;
    tile[kk][nc + 2] = v.z;
    tile[kk][nc + 3] = v.w;
  }
  __syncthreads();
  int np = t >> 2, c = t & 3;
  u16* dp = dst + (size_t)(dstRow + np) * K + k0;
  u16 pk[8];
  #pragma unroll
  for (int j = 0; j < 8; j++) pk[j] = f2bf(tile[c*8 + j][np]);
  *(int4*)(dp + c*8) = *(int4*)pk;
  #pragma unroll
  for (int j = 0; j < 8; j++) pk[j] = f2bf(tile[32 + c*8 + j][np]);
  *(int4*)(dp + 32 + c*8) = *(int4*)pk;
}

__global__ __launch_bounds__(256) void transpose_w(const float* __restrict__ Bw,
                                                   u16* __restrict__ Bt,
                                                   int N, int K, int c0){
  int n0 = blockIdx.x * 64, k0 = blockIdx.y * 64;
  trans_tile(Bw, Bt, N, K, c0 + n0, n0, k0);
}

// all layer weights + head in ONE dispatch.
__global__ __launch_bounds__(256) void mega_transpose(const float* __restrict__ qkvw,
                                                      const float* __restrict__ fc1w,
                                                      const float* __restrict__ fc2w,
                                                      const float* __restrict__ headw,
                                                      u16* __restrict__ Wq,
                                                      u16* __restrict__ W1,
                                                      u16* __restrict__ W2,
                                                      u16* __restrict__ Wh){
  int id = blockIdx.x;
  const float* src; u16* dst; int N, K, n0, k0;
  if (id < 6144){
    int l = id / 768, r = id % 768;
    n0 = (r % 48) * 64; k0 = (r / 48) * 64;
    src = qkvw + (size_t)l * Dm * 3072; dst = Wq + (size_t)l * 3072 * Dm;
    N = 3072; K = Dm;
  } else if (id < 14336){
    int id2 = id - 6144;
    int l = id2 / 1024, r = id2 % 1024;
    n0 = (r % 64) * 64; k0 = (r / 64) * 64;
    src = fc1w + (size_t)l * Dm * Fm; dst = W1 + (size_t)l * Fm * Dm;
    N = Fm; K = Dm;
  } else if (id < 22528){
    int id2 = id - 14336;
    int l = id2 / 1024, r = id2 % 1024;
    n0 = (r % 16) * 64; k0 = (r / 16) * 64;
    src = fc2w + (size_t)l * Fm * Dm; dst = W2 + (size_t)l * Dm * Fm;
    N = Dm; K = Fm;
  } else {
    int id2 = id - 22528;
    n0 = (id2 % 788) * 64; k0 = (id2 / 788) * 64;   // 50432 rows, zero-filled past 50257
    src = headw; dst = Wh;
    N = Vn; K = Dm;
  }
  trans_tile(src, dst, N, K, n0, n0, k0);
}

// ---------------- generic 2-phase GEMM (layer GEMMs + fallback) ----------------
template<int MODE, int BMt, int BNt, int WM, int WN, bool SWZ>
__global__ __launch_bounds__(256) void gemm_kernel(const u16* __restrict__ A,
                                                   const u16* __restrict__ Bt,
                                                   const float* __restrict__ bias,
                                                   void* __restrict__ outp,
                                                   float* __restrict__ resid,
                                                   u16* __restrict__ vT,
                                                   int K, int Nout, int c0){
  constexpr int MR = BMt / (WM * 16);
  constexpr int NR = BNt / (WN * 16);
  __shared__ u16 sA[BMt][64];
  __shared__ u16 sB[BNt][64];
  int t = threadIdx.x;
  int lane = t & 63, w = t >> 6;
  int wm = w / WN, wn = w % WN;
  int lr = lane & 15, lg = lane >> 4;
  int m0, n0;
  if (SWZ){
    int orig = blockIdx.x;
    int q = gridDim.x >> 3;
    int wg = (orig & 7) * q + (orig >> 3);
    m0 = (wg & 15) * BMt;
    n0 = (wg >> 4) * BNt;
  } else {
    m0 = blockIdx.y * BMt; n0 = blockIdx.x * BNt;
  }

  f32x4 acc[MR][NR] = {};

  int srow = lane >> 3;
  int gcs = ((lane & 7) ^ (lane >> 3)) * 8;        // pre-swizzled global k-col (u16)
  int cswz = (lr & 7) << 3;                        // read-side swizzle

  for (int k0 = 0; k0 < K; k0 += 64){
    __syncthreads();
    #pragma unroll
    for (int i = 0; i < BMt/32; i++){
      int rbase = i*32 + w*8;
      gload16(A + (size_t)(m0 + rbase + srow) * K + k0 + gcs, (char*)&sA[rbase][0]);
    }
    #pragma unroll
    for (int i = 0; i < BNt/32; i++){
      int rbase = i*32 + w*8;
      gload16(Bt + (size_t)(n0 + rbase + srow) * K + k0 + gcs, (char*)&sB[rbase][0]);
    }
    __syncthreads();
    #pragma unroll
    for (int kk = 0; kk < 2; kk++){
      bf16x8 af[MR], bfr[NR];
      #pragma unroll
      for (int i = 0; i < MR; i++) af[i]  = *(const bf16x8*)&sA[wm*(MR*16) + i*16 + lr][(kk*32 + lg*8) ^ cswz];
      #pragma unroll
      for (int j = 0; j < NR; j++) bfr[j] = *(const bf16x8*)&sB[wn*(NR*16) + j*16 + lr][(kk*32 + lg*8) ^ cswz];
      #pragma unroll
      for (int i = 0; i < MR; i++)
        #pragma unroll
        for (int j = 0; j < NR; j++)
          acc[i][j] = __builtin_amdgcn_mfma_f32_16x16x32_bf16(af[i], bfr[j], acc[i][j], 0, 0, 0);
    }
  }

  #pragma unroll
  for (int i = 0; i < MR; i++){
    int gr0 = m0 + wm*(MR*16) + i*16 + lg*4;
    #pragma unroll
    for (int j = 0; j < NR; j++){
      int gc = c0 + n0 + wn*(NR*16) + j*16 + lr;
      if (MODE == 3 && gc >= Nout) continue;
      float bb = bias[gc];
      if (MODE == 0 && gc >= 2048){
        int hh = (gc - 2048) >> 6, dd = (gc - 2048) & 63;
        int b_ = gr0 >> 10, tt = gr0 & 1023;
        u16 pk[4];
        #pragma unroll
        for (int r = 0; r < 4; r++) pk[r] = f2bf(acc[i][j][r] + bb);
        *(uint2*)&vT[((size_t)((b_*Hn + hh)*64 + dd))*Tn + tt] = *(uint2*)pk;
        continue;
      }
      #pragma unroll
      for (int r = 0; r < 4; r++){
        float v = acc[i][j][r] + bb;
        size_t oi = (size_t)(gr0 + r) * Nout + gc;
        if (MODE == 0)      ((u16*)outp)[oi] = f2bf(v);
        else if (MODE == 1) ((u16*)outp)[oi] = f2bf(gelu_f(v));
        else if (MODE == 2) resid[oi] = resid[oi] + gelu_f(v);
        else                ((float*)outp)[oi] = v;
      }
    }
  }
}

// ---------------- 8-phase 256x256 head GEMM, 16 waves (4M x 4N) ----------------
// Same schedule skeleton as r6 (best measured head), but 1024 threads:
// 4 waves/SIMD hides ds_read latency; acc[4][4] (64 VGPR) per wave; staging is
// 1 gload16/thread per 16KB half-tile slot; counted waits uniform vmcnt(2).
#define BARR() __builtin_amdgcn_s_barrier()
#define LGK0() asm volatile("s_waitcnt lgkmcnt(0)" ::: "memory")
#define VMC2() asm volatile("s_waitcnt vmcnt(2)" ::: "memory")

__global__ __launch_bounds__(1024) void head_gemm_8ph(const u16* __restrict__ A,
                                                      const u16* __restrict__ Bw,
                                                      const float* __restrict__ bias,
                                                      float* __restrict__ out){
  __shared__ u16 sA[2][256][64];
  __shared__ u16 sB[2][256][64];
  int t = threadIdx.x, lane = t & 63, w = t >> 6;   // w 0..15
  int wm = w >> 2, wn = w & 3;                      // 4 x 4 wave grid
  int lr = lane & 15, lg = lane >> 4;
  int orig = blockIdx.x;
  int wg = (orig & 7) * (gridDim.x >> 3) + (orig >> 3);  // XCD-chunked (1576 % 8 == 0)
  int m0g = (wg & 7) << 8;                                // m-fastest: B-panel reuse in-XCD
  int n0g = (wg >> 3) << 8;

  int srow = t >> 3;                               // 0..127 within a half
  int scol = ((t & 7) ^ ((t >> 3) & 7)) * 8;       // pre-swizzled source col (u16)
  const u16* Abase = A  + (size_t)(m0g + srow) * 1024 + scol;
  const u16* Bbase = Bw + (size_t)(n0g + srow) * 1024 + scol;

  f32x4 acc[4][4] = {};
  bf16x8 a[2][2], b0[2][2], b1[2][2];
  int rsw = (lr & 7) << 3;

  auto stA = [&](int buf, int half, int tile){
    gload16(Abase + (size_t)half*128*1024 + tile*64, &sA[buf][half*128 + w*8][0]);
  };
  auto stB = [&](int buf, int half, int tile){
    gload16(Bbase + (size_t)half*128*1024 + tile*64, &sB[buf][half*128 + w*8][0]);
  };
  auto rdA = [&](int buf, int half){
    #pragma unroll
    for (int i = 0; i < 2; i++)
      #pragma unroll
      for (int kk = 0; kk < 2; kk++)
        a[i][kk] = *(const bf16x8*)&sA[buf][wm*64 + half*32 + i*16 + lr][(kk*32 + lg*8) ^ rsw];
  };
  auto rdB = [&](int buf, int half, bf16x8 (&bb)[2][2]){
    #pragma unroll
    for (int j = 0; j < 2; j++)
      #pragma unroll
      for (int kk = 0; kk < 2; kk++)
        bb[j][kk] = *(const bf16x8*)&sB[buf][wn*64 + half*32 + j*16 + lr][(kk*32 + lg*8) ^ rsw];
  };
  auto MF = [&](int mb, int nb, bf16x8 (&bb)[2][2]){
    __builtin_amdgcn_s_setprio(1);
    #pragma unroll
    for (int kk = 0; kk < 2; kk++)
      #pragma unroll
      for (int i = 0; i < 2; i++)
        #pragma unroll
        for (int j = 0; j < 2; j++)
          acc[mb+i][nb+j] = __builtin_amdgcn_mfma_f32_16x16x32_bf16(a[i][kk], bb[j][kk], acc[mb+i][nb+j], 0, 0, 0);
    __builtin_amdgcn_s_setprio(0);
  };

  // prologue: tile0 full + tile1 B; allow tile1's 2 B-loads in flight
  stA(0,0,0); stA(0,1,0); stB(0,0,0); stB(0,1,0);
  stB(1,0,1); stB(1,1,1);
  VMC2();
  BARR();

  for (int it = 0; it < 8; ++it){
    int T = it * 2;
    // ---- tile T (buf0) ----
    rdA(0,0); rdB(0,0,b0);                 // P1
    stA(1,0,T+1);
    BARR(); LGK0(); MF(0,0,b0); BARR();
    rdB(0,1,b1);                           // P2
    stA(1,1,T+1);
    BARR(); LGK0(); MF(0,2,b1); BARR();
    rdA(0,1);                              // P3
    if (T+2 < 16) stB(0,0,T+2);
    BARR(); LGK0(); MF(2,2,b1); BARR();
    if (T+2 < 16) stB(0,1,T+2);            // P4
    BARR(); MF(2,0,b0); VMC2(); BARR();
    // ---- tile T+1 (buf1) ----
    rdA(1,0); rdB(1,0,b0);                 // P5
    if (T+2 < 16) stA(0,0,T+2);
    BARR(); LGK0(); MF(0,0,b0); BARR();
    rdB(1,1,b1);                           // P6
    if (T+2 < 16) stA(0,1,T+2);
    BARR(); LGK0(); MF(0,2,b1); BARR();
    rdA(1,1);                              // P7
    if (T+3 < 16) stB(1,0,T+3);
    BARR(); LGK0(); MF(2,2,b1); BARR();
    if (T+3 < 16) stB(1,1,T+3);            // P8
    BARR(); MF(2,0,b0); VMC2(); BARR();
  }

  #pragma unroll
  for (int m = 0; m < 4; m++){
    int gr = m0g + wm*64 + m*16 + lg*4;
    #pragma unroll
    for (int n = 0; n < 4; n++){
      int gc = n0g + wn*64 + n*16 + lr;
      if (gc < Vn){
        float bb = bias[gc];
        #pragma unroll
        for (int r = 0; r < 4; r++)
          out[(size_t)(gr + r) * Vn + gc] = acc[m][n][r] + bb;
      }
    }
  }
}

// ---------------- MFMA fused causal attention (dbuf K/V, T14 staging, T13 defer-max) ----------------
__global__ __launch_bounds__(256) void attn_mfma(const u16* __restrict__ qkv,
                                                 const u16* __restrict__ vT,
                                                 float* __restrict__ x){
  int bid = blockIdx.x;
  int bh = bid & 31;
  int j = bid >> 5;
  int qt = (j < 8) ? (15 - j) : (j - 8);
  int b = bh >> 4, h_ = bh & 15;
  int t = threadIdx.x;
  int w = t >> 6, lane = t & 63;
  int lr = lane & 15, lg = lane >> 4;

  __shared__ u16 sK [2][64][72];
  __shared__ u16 sVt[2][64][72];
  __shared__ u16 sP [64][72];

  const u16* qbase = qkv + ((size_t)(b*Tn + qt*64 + w*16 + lr)) * 3*Dm + h_*64 + lg*8;
  bf16x8 qf[2];
  #pragma unroll
  for (int i = 0; i < 2; i++){
    u16x8 raw = *(const u16x8*)(qbase + i * 32);
    #pragma unroll
    for (int u = 0; u < 8; u++) qf[i][u] = (__bf16)(bf2f(raw[u]) * 0.03125f);
  }

  f32x4 o_[4] = {};
  float m_[4], l_[4];
  #pragma unroll
  for (int r = 0; r < 4; r++){ m_[r] = -INFINITY; l_[r] = 0.0f; }

  int sr = t >> 2, scc = (t & 3) * 16;
  const u16* kbase = qkv + ((size_t)(b*Tn + sr)) * 3*Dm + Dm + h_*64 + scc;
  const u16* vbase = vT + ((size_t)(bh*64 + sr)) * Tn + scc;
  int4 kr0, kr1, vr0, vr1;

  kr0 = *(const int4*)(kbase);     kr1 = *(const int4*)(kbase + 8);
  vr0 = *(const int4*)(vbase);     vr1 = *(const int4*)(vbase + 8);
  *(int4*)&sK [0][sr][scc]     = kr0;  *(int4*)&sK [0][sr][scc + 8] = kr1;
  *(int4*)&sVt[0][sr][scc]     = vr0;  *(int4*)&sVt[0][sr][scc + 8] = vr1;

  for (int kt = 0; kt <= qt; kt++){
    int cur = kt & 1;
    if (kt < qt){                  // T14: issue next tile's loads before compute
      const u16* kb = kbase + (size_t)(kt + 1) * 64 * 3 * Dm;
      const u16* vb = vbase + (kt + 1) * 64;
      kr0 = *(const int4*)(kb);    kr1 = *(const int4*)(kb + 8);
      vr0 = *(const int4*)(vb);    vr1 = *(const int4*)(vb + 8);
    }
    __syncthreads();

    f32x4 s[4] = {};
    __builtin_amdgcn_s_setprio(1);
    #pragma unroll
    for (int kf = 0; kf < 2; kf++){
      #pragma unroll
      for (int nf = 0; nf < 4; nf++){
        bf16x8 kfrag = *(const bf16x8*)&sK[cur][nf*16 + lr][kf*32 + lg*8];
        s[nf] = __builtin_amdgcn_mfma_f32_16x16x32_bf16(qf[kf], kfrag, s[nf], 0, 0, 0);
      }
    }
    __builtin_amdgcn_s_setprio(0);

    bool lastt = (kt == qt);
    float tmax[4] = {-INFINITY, -INFINITY, -INFINITY, -INFINITY};
    #pragma unroll
    for (int nf = 0; nf < 4; nf++)
      #pragma unroll
      for (int r = 0; r < 4; r++){
        float v = s[nf][r];
        if (lastt){
          int kkg = nf*16 + lr, qg = w*16 + lg*4 + r;
          if (kkg > qg) v = -INFINITY;
        }
        s[nf][r] = v;
        tmax[r] = fmaxf(tmax[r], v);
      }
    #pragma unroll
    for (int r = 0; r < 4; r++){
      tmax[r] = fmaxf(tmax[r], __shfl_xor(tmax[r], 1));
      tmax[r] = fmaxf(tmax[r], __shfl_xor(tmax[r], 2));
      tmax[r] = fmaxf(tmax[r], __shfl_xor(tmax[r], 4));
      tmax[r] = fmaxf(tmax[r], __shfl_xor(tmax[r], 8));
    }
    // T13 defer-max: skip rescale while per-row growth <= 8 (P bounded by e^8, f32-safe)
    bool need = false;
    #pragma unroll
    for (int r = 0; r < 4; r++) need = need || (tmax[r] > m_[r] + 8.0f);
    if (__any(need)){
      #pragma unroll
      for (int r = 0; r < 4; r++){
        float nm = fmaxf(m_[r], tmax[r]);
        float resc = __expf(m_[r] - nm);
        m_[r] = nm;
        l_[r] *= resc;
        #pragma unroll
        for (int df = 0; df < 4; df++) o_[df][r] *= resc;
      }
    }
    float psum[4] = {0.f, 0.f, 0.f, 0.f};
    #pragma unroll
    for (int nf = 0; nf < 4; nf++)
      #pragma unroll
      for (int r = 0; r < 4; r++){
        float pv = __expf(s[nf][r] - m_[r]);
        s[nf][r] = pv;
        psum[r] += pv;
      }
    #pragma unroll
    for (int r = 0; r < 4; r++){
      psum[r] += __shfl_xor(psum[r], 1);
      psum[r] += __shfl_xor(psum[r], 2);
      psum[r] += __shfl_xor(psum[r], 4);
      psum[r] += __shfl_xor(psum[r], 8);
      l_[r] += psum[r];
    }

    #pragma unroll
    for (int nf = 0; nf < 4; nf++)
      #pragma unroll
      for (int r = 0; r < 4; r++)
        sP[w*16 + lg*4 + r][nf*16 + lr] = f2bf(s[nf][r]);

    __builtin_amdgcn_s_setprio(1);
    #pragma unroll
    for (int kf = 0; kf < 2; kf++){
      bf16x8 pfrag = *(const bf16x8*)&sP[w*16 + lr][kf*32 + lg*8];
      #pragma unroll
      for (int df = 0; df < 4; df++){
        bf16x8 vfrag = *(const bf16x8*)&sVt[cur][df*16 + lr][kf*32 + lg*8];
        o_[df] = __builtin_amdgcn_mfma_f32_16x16x32_bf16(pfrag, vfrag, o_[df], 0, 0, 0);
      }
    }
    __builtin_amdgcn_s_setprio(0);

    if (kt < qt){                  // write-late: land next tile in the other buffer
      int nxt = cur ^ 1;
      *(int4*)&sK [nxt][sr][scc]     = kr0;  *(int4*)&sK [nxt][sr][scc + 8] = kr1;
      *(int4*)&sVt[nxt][sr][scc]     = vr0;  *(int4*)&sVt[nxt][sr][scc + 8] = vr1;
    }
  }

  float inv[4];
  #pragma unroll
  for (int r = 0; r < 4; r++) inv[r] = 1.0f / l_[r];
  #pragma unroll
  for (int df = 0; df < 4; df++)
    #pragma unroll
    for (int r = 0; r < 4; r++){
      float* xr = x + ((size_t)(b*Tn + qt*64 + w*16 + lg*4 + r)) * Dm + h_*64 + df*16 + lr;
      *xr += o_[df][r] * inv[r];
    }
}

// ---------------- host orchestration ----------------
extern "C" void kernel_launch(void* const* d_in, const int* in_sizes, int n_in,
                              void* d_out, int out_size, void* d_ws, size_t ws_size,
                              hipStream_t stream){
  const int*   idx   = (const int*)  d_in[0];
  const float* emb   = (const float*)d_in[1];
  const float* pos   = (const float*)d_in[2];
  const float* ln1w  = (const float*)d_in[3];
  const float* ln1b  = (const float*)d_in[4];
  const float* qkvw  = (const float*)d_in[5];
  const float* qkvb  = (const float*)d_in[6];
  const float* ln2w  = (const float*)d_in[7];
  const float* ln2b  = (const float*)d_in[8];
  const float* fc1w  = (const float*)d_in[9];
  const float* fc1b  = (const float*)d_in[10];
  const float* fc2w  = (const float*)d_in[11];
  const float* fc2b  = (const float*)d_in[12];
  const float* lnfw  = (const float*)d_in[13];
  const float* lnfb  = (const float*)d_in[14];
  const float* headw = (const float*)d_in[15];
  const float* headb = (const float*)d_in[16];
  float* out = (float*)d_out;

  const size_t MB = 1u << 20;
  char* ws = (char*)d_ws;
  float* x   = (float*)(ws);                       // 8 MB  [2048][1024] f32
  u16*   h   = (u16*)  (ws + 8*MB);                // 4 MB  [2048][1024] bf16
  u16*   qkv = (u16*)  (ws + 12*MB);               // 12 MB [2048][3072] bf16
  u16*   f1  = (u16*)  (ws + 24*MB);               // 16 MB [2048][4096] bf16

  bool mega    = ws_size >= 320*MB;
  bool bighead = ws_size >= 116*MB;

  u16 *vT, *Bt = nullptr, *BtF = nullptr, *Wq = nullptr, *W1 = nullptr, *W2 = nullptr, *Wh = nullptr;
  if (mega){
    vT = (u16*)(ws + 40*MB);                       // 4 MB
    Wq = (u16*)(ws + 44*MB);                       // 48 MB  (8 x 3072x1024)
    W1 = (u16*)(ws + 92*MB);                       // 64 MB  (8 x 4096x1024)
    W2 = (u16*)(ws + 156*MB);                      // 64 MB  (8 x 1024x4096)
    Wh = (u16*)(ws + 220*MB);                      // 98.5 MiB (50432x1024)
  } else {
    Bt  = (u16*)(ws + 40*MB);
    vT  = (u16*)(ws + 48*MB);
    BtF = (u16*)(ws + 12*MB);
  }

  if (mega)
    mega_transpose<<<35136, 256, 0, stream>>>(qkvw, fc1w, fc2w, headw, Wq, W1, W2, Wh);

  embed_kernel<<<NTOK, 256, 0, stream>>>(idx, emb, pos, x);

  for (int l = 0; l < Ln; l++){
    const u16* Bq = mega ? Wq + (size_t)l*3072*Dm : Bt;
    const u16* B1 = mega ? W1 + (size_t)l*Fm*Dm   : Bt;
    const u16* B2 = mega ? W2 + (size_t)l*Dm*Fm   : Bt;
    // --- attention block ---
    ln_kernel<<<NTOK, 256, 0, stream>>>(x, ln1w + l*Dm, ln1b + l*Dm, h);
    if (!mega) transpose_w<<<dim3(3072/64, Dm/64), 256, 0, stream>>>(qkvw + (size_t)l*Dm*3072, Bt, 3072, Dm, 0);
    gemm_kernel<0, 64,128,1,4,false><<<dim3(3072/128, NTOK/64), 256, 0, stream>>>(h, Bq, qkvb + l*3072, qkv, nullptr, vT, Dm, 3072, 0);
    attn_mfma<<<512, 256, 0, stream>>>(qkv, vT, x);
    // --- MLP block ---
    ln_kernel<<<NTOK, 256, 0, stream>>>(x, ln2w + l*Dm, ln2b + l*Dm, h);
    if (!mega) transpose_w<<<dim3(Fm/64, Dm/64), 256, 0, stream>>>(fc1w + (size_t)l*Dm*Fm, Bt, Fm, Dm, 0);
    gemm_kernel<1,128,128,2,2,false><<<dim3(Fm/128, NTOK/128), 256, 0, stream>>>(h, B1, fc1b + l*Fm, f1, nullptr, nullptr, Dm, Fm, 0);
    if (!mega) transpose_w<<<dim3(Dm/64, Fm/64), 256, 0, stream>>>(fc2w + (size_t)l*Fm*Dm, Bt, Dm, Fm, 0);
    gemm_kernel<2, 64,64,2,2,false><<<dim3(Dm/64, NTOK/64), 256, 0, stream>>>(f1, B2, fc2b + l*Dm, nullptr, x, nullptr, Fm, Dm, 0);
  }

  ln_kernel<<<NTOK, 256, 0, stream>>>(x, lnfw, lnfb, h);

  if (mega){
    head_gemm_8ph<<<1576, 1024, 0, stream>>>(h, Wh, headb, out);   // 8 m x 197 n tiles, 16 waves
  } else if (bighead){
    transpose_w<<<dim3(786, Dm/64), 256, 0, stream>>>(headw, BtF, Vn, Dm, 0);
    gemm_kernel<3,128,128,2,2,true><<<6288, 256, 0, stream>>>(h, BtF, headb, out, nullptr, nullptr, Dm, Vn, 0);
  } else {
    const int CHUNK = 4096;
    for (int c0 = 0; c0 < Vn; c0 += CHUNK){
      int W = Vn - c0; if (W > CHUNK) W = CHUNK;
      int ngx = (W + 127) / 128;
      transpose_w<<<dim3(ngx * 2, Dm/64), 256, 0, stream>>>(headw, Bt, Vn, Dm, c0);
      gemm_kernel<3,128,128,2,2,false><<<dim3(ngx, NTOK/128), 256, 0, stream>>>(h, Bt, headb, out, nullptr, nullptr, Dm, Vn, c0);
    }
  }
}

// Round 11
// 1790.906 us; speedup vs baseline: 1.3110x; 1.0068x over previous
//
#include <hip/hip_runtime.h>
#include <math.h>

#define Ln 8
#define Bn 2
#define Tn 1024
#define Dm 1024
#define Hn 16
#define Fm 4096
#define Vn 50257
#define NTOK 2048   // B*T

typedef unsigned short u16;
typedef u16   u16x8  __attribute__((ext_vector_type(8)));
typedef __bf16 bf16x8 __attribute__((ext_vector_type(8)));
typedef float f32x4  __attribute__((ext_vector_type(4)));

__device__ __forceinline__ u16 f2bf(float f){
  unsigned u = __builtin_bit_cast(unsigned, f);
  u += 0x7FFFu + ((u >> 16) & 1u);            // RNE
  return (u16)(u >> 16);
}
__device__ __forceinline__ float bf2f(u16 s){
  return __builtin_bit_cast(float, ((unsigned)s) << 16);
}
__device__ __forceinline__ float gelu_f(float v){
  return 0.5f * v * (1.0f + erff(v * 0.70710678118654752440f));
}
__device__ __forceinline__ void gload16(const void* g, void* l){
  __builtin_amdgcn_global_load_lds(
      (const __attribute__((address_space(1))) void*)g,
      (__attribute__((address_space(3))) void*)l, 16, 0, 0);
}

// ---------------- embedding ----------------
__global__ __launch_bounds__(256) void embed_kernel(const int* __restrict__ idx,
                                                    const float* __restrict__ emb,
                                                    const float* __restrict__ pos,
                                                    float* __restrict__ x){
  int row = blockIdx.x;
  int t = row & (Tn - 1);
  int id = idx[row];
  const float4* e = (const float4*)(emb + (size_t)id * Dm);
  const float4* p = (const float4*)(pos + (size_t)t * Dm);
  float4* o = (float4*)(x + (size_t)row * Dm);
  int i = threadIdx.x;
  float4 a = e[i], b = p[i];
  o[i] = make_float4(a.x + b.x, a.y + b.y, a.z + b.z, a.w + b.w);
}

// ---------------- layernorm (f32 in, bf16 out) ----------------
__global__ __launch_bounds__(256) void ln_kernel(const float* __restrict__ xin,
                                                 const float* __restrict__ w,
                                                 const float* __restrict__ bb,
                                                 u16* __restrict__ out){
  int row = blockIdx.x;
  int t = threadIdx.x;
  float4 v = ((const float4*)(xin + (size_t)row * Dm))[t];
  float s  = v.x + v.y + v.z + v.w;
  float s2 = v.x*v.x + v.y*v.y + v.z*v.z + v.w*v.w;
  #pragma unroll
  for (int off = 1; off < 64; off <<= 1){
    s  += __shfl_xor(s, off);
    s2 += __shfl_xor(s2, off);
  }
  __shared__ float red[8];
  int wv = t >> 6, lane = t & 63;
  if (lane == 0){ red[wv] = s; red[4 + wv] = s2; }
  __syncthreads();
  s  = red[0] + red[1] + red[2] + red[3];
  s2 = red[4] + red[5] + red[6] + red[7];
  float mean = s * (1.0f / Dm);
  float var  = s2 * (1.0f / Dm) - mean * mean;
  float rs = rsqrtf(var + 1e-5f);
  float4 wv4 = ((const float4*)w)[t];
  float4 bv4 = ((const float4*)bb)[t];
  u16 o4[4];
  o4[0] = f2bf((v.x - mean) * rs * wv4.x + bv4.x);
  o4[1] = f2bf((v.y - mean) * rs * wv4.y + bv4.y);
  o4[2] = f2bf((v.z - mean) * rs * wv4.z + bv4.z);
  o4[3] = f2bf((v.w - mean) * rs * wv4.w + bv4.w);
  *(uint2*)(out + (size_t)row * Dm + t * 4) = *(uint2*)o4;
}

// ---------------- transpose tile: f32 src[k][srcCol+*] -> bf16 dst[dstRow+*][k] ----------------
__device__ __forceinline__ void trans_tile(const float* __restrict__ src,
                                           u16* __restrict__ dst,
                                           int N, int K, int srcCol, int dstRow, int k0){
  __shared__ float tile[64][66];
  int t = threadIdx.x;
  int rr = t >> 4, nc = (t & 15) * 4;
  #pragma unroll
  for (int u = 0; u < 4; u++){
    int kk = rr + u * 16;
    int gn = srcCol + nc;
    const float* sp = src + (size_t)(k0 + kk) * N;
    float4 v;
    if (gn + 3 < N) v = *(const float4*)(sp + gn);
    else {
      v.x = (gn     < N) ? sp[gn]     : 0.0f;
      v.y = (gn + 1 < N) ? sp[gn + 1] : 0.0f;
      v.z = (gn + 2 < N) ? sp[gn + 2] : 0.0f;
      v.w = (gn + 3 < N) ? sp[gn + 3] : 0.0f;
    }
    tile[kk][nc]     = v.x;
    tile[kk][nc + 1] = v.y;
    tile[kk][nc + 2] = v.z;
    tile[kk][nc + 3] = v.w;
  }
  __syncthreads();
  int np = t >> 2, c = t & 3;
  u16* dp = dst + (size_t)(dstRow + np) * K + k0;
  u16 pk[8];
  #pragma unroll
  for (int j = 0; j < 8; j++) pk[j] = f2bf(tile[c*8 + j][np]);
  *(int4*)(dp + c*8) = *(int4*)pk;
  #pragma unroll
  for (int j = 0; j < 8; j++) pk[j] = f2bf(tile[32 + c*8 + j][np]);
  *(int4*)(dp + 32 + c*8) = *(int4*)pk;
}

__global__ __launch_bounds__(256) void transpose_w(const float* __restrict__ Bw,
                                                   u16* __restrict__ Bt,
                                                   int N, int K, int c0){
  int n0 = blockIdx.x * 64, k0 = blockIdx.y * 64;
  trans_tile(Bw, Bt, N, K, c0 + n0, n0, k0);
}

// all layer weights + head in ONE dispatch.
__global__ __launch_bounds__(256) void mega_transpose(const float* __restrict__ qkvw,
                                                      const float* __restrict__ fc1w,
                                                      const float* __restrict__ fc2w,
                                                      const float* __restrict__ headw,
                                                      u16* __restrict__ Wq,
                                                      u16* __restrict__ W1,
                                                      u16* __restrict__ W2,
                                                      u16* __restrict__ Wh){
  int id = blockIdx.x;
  const float* src; u16* dst; int N, K, n0, k0;
  if (id < 6144){
    int l = id / 768, r = id % 768;
    n0 = (r % 48) * 64; k0 = (r / 48) * 64;
    src = qkvw + (size_t)l * Dm * 3072; dst = Wq + (size_t)l * 3072 * Dm;
    N = 3072; K = Dm;
  } else if (id < 14336){
    int id2 = id - 6144;
    int l = id2 / 1024, r = id2 % 1024;
    n0 = (r % 64) * 64; k0 = (r / 64) * 64;
    src = fc1w + (size_t)l * Dm * Fm; dst = W1 + (size_t)l * Fm * Dm;
    N = Fm; K = Dm;
  } else if (id < 22528){
    int id2 = id - 14336;
    int l = id2 / 1024, r = id2 % 1024;
    n0 = (r % 16) * 64; k0 = (r / 16) * 64;
    src = fc2w + (size_t)l * Fm * Dm; dst = W2 + (size_t)l * Dm * Fm;
    N = Dm; K = Fm;
  } else {
    int id2 = id - 22528;
    n0 = (id2 % 788) * 64; k0 = (id2 / 788) * 64;   // 50432 rows, zero-filled past 50257
    src = headw; dst = Wh;
    N = Vn; K = Dm;
  }
  trans_tile(src, dst, N, K, n0, n0, k0);
}

// ---------------- generic 2-phase GEMM (layer GEMMs + fallback) ----------------
template<int MODE, int BMt, int BNt, int WM, int WN, bool SWZ>
__global__ __launch_bounds__(256) void gemm_kernel(const u16* __restrict__ A,
                                                   const u16* __restrict__ Bt,
                                                   const float* __restrict__ bias,
                                                   void* __restrict__ outp,
                                                   float* __restrict__ resid,
                                                   u16* __restrict__ vT,
                                                   int K, int Nout, int c0){
  constexpr int MR = BMt / (WM * 16);
  constexpr int NR = BNt / (WN * 16);
  __shared__ u16 sA[BMt][64];
  __shared__ u16 sB[BNt][64];
  int t = threadIdx.x;
  int lane = t & 63, w = t >> 6;
  int wm = w / WN, wn = w % WN;
  int lr = lane & 15, lg = lane >> 4;
  int m0, n0;
  if (SWZ){
    int orig = blockIdx.x;
    int q = gridDim.x >> 3;
    int wg = (orig & 7) * q + (orig >> 3);
    m0 = (wg & 15) * BMt;
    n0 = (wg >> 4) * BNt;
  } else {
    m0 = blockIdx.y * BMt; n0 = blockIdx.x * BNt;
  }

  f32x4 acc[MR][NR] = {};

  int srow = lane >> 3;
  int gcs = ((lane & 7) ^ (lane >> 3)) * 8;        // pre-swizzled global k-col (u16)
  int cswz = (lr & 7) << 3;                        // read-side swizzle

  for (int k0 = 0; k0 < K; k0 += 64){
    __syncthreads();
    #pragma unroll
    for (int i = 0; i < BMt/32; i++){
      int rbase = i*32 + w*8;
      gload16(A + (size_t)(m0 + rbase + srow) * K + k0 + gcs, (char*)&sA[rbase][0]);
    }
    #pragma unroll
    for (int i = 0; i < BNt/32; i++){
      int rbase = i*32 + w*8;
      gload16(Bt + (size_t)(n0 + rbase + srow) * K + k0 + gcs, (char*)&sB[rbase][0]);
    }
    __syncthreads();
    #pragma unroll
    for (int kk = 0; kk < 2; kk++){
      bf16x8 af[MR], bfr[NR];
      #pragma unroll
      for (int i = 0; i < MR; i++) af[i]  = *(const bf16x8*)&sA[wm*(MR*16) + i*16 + lr][(kk*32 + lg*8) ^ cswz];
      #pragma unroll
      for (int j = 0; j < NR; j++) bfr[j] = *(const bf16x8*)&sB[wn*(NR*16) + j*16 + lr][(kk*32 + lg*8) ^ cswz];
      #pragma unroll
      for (int i = 0; i < MR; i++)
        #pragma unroll
        for (int j = 0; j < NR; j++)
          acc[i][j] = __builtin_amdgcn_mfma_f32_16x16x32_bf16(af[i], bfr[j], acc[i][j], 0, 0, 0);
    }
  }

  #pragma unroll
  for (int i = 0; i < MR; i++){
    int gr0 = m0 + wm*(MR*16) + i*16 + lg*4;
    #pragma unroll
    for (int j = 0; j < NR; j++){
      int gc = c0 + n0 + wn*(NR*16) + j*16 + lr;
      if (MODE == 3 && gc >= Nout) continue;
      float bb = bias[gc];
      if (MODE == 0 && gc >= 2048){
        int hh = (gc - 2048) >> 6, dd = (gc - 2048) & 63;
        int b_ = gr0 >> 10, tt = gr0 & 1023;
        u16 pk[4];
        #pragma unroll
        for (int r = 0; r < 4; r++) pk[r] = f2bf(acc[i][j][r] + bb);
        *(uint2*)&vT[((size_t)((b_*Hn + hh)*64 + dd))*Tn + tt] = *(uint2*)pk;
        continue;
      }
      #pragma unroll
      for (int r = 0; r < 4; r++){
        float v = acc[i][j][r] + bb;
        size_t oi = (size_t)(gr0 + r) * Nout + gc;
        if (MODE == 0)      ((u16*)outp)[oi] = f2bf(v);
        else if (MODE == 1) ((u16*)outp)[oi] = f2bf(gelu_f(v));
        else if (MODE == 2) resid[oi] = resid[oi] + gelu_f(v);
        else                ((float*)outp)[oi] = v;
      }
    }
  }
}

// ---------------- 8-phase 256x256 head GEMM (512 thr, r8-best) + store-overlap tail ----------------
// Final iteration peeled: each acc quadrant's stores issue right after its last MFMA
// (P5..P8 of it=7), overlapping the 256KB f32 epilogue with remaining compute.
// Peeled P4 uses vmcnt(0) (free there; also guarantees tile-15 staging landed).
#define BARR() __builtin_amdgcn_s_barrier()
#define LGK0() asm volatile("s_waitcnt lgkmcnt(0)" ::: "memory")
#define VMC4() asm volatile("s_waitcnt vmcnt(4)" ::: "memory")
#define VMC0() asm volatile("s_waitcnt vmcnt(0)" ::: "memory")

__global__ __launch_bounds__(512) void head_gemm_8ph(const u16* __restrict__ A,
                                                     const u16* __restrict__ Bw,
                                                     const float* __restrict__ bias,
                                                     float* __restrict__ out){
  __shared__ u16 sA[2][256][64];
  __shared__ u16 sB[2][256][64];
  int t = threadIdx.x, lane = t & 63, w = t >> 6;
  int wm = w >> 2, wn = w & 3;
  int lr = lane & 15, lg = lane >> 4;
  int orig = blockIdx.x;
  int wg = (orig & 7) * (gridDim.x >> 3) + (orig >> 3);  // XCD-chunked (1576 % 8 == 0)
  int m0g = (wg & 7) << 8;                                // m-fastest: B-panel reuse in-XCD
  int n0g = (wg >> 3) << 8;

  int srow = w*8 + (lane >> 3);
  int scol = ((lane & 7) ^ (lane >> 3)) * 8;     // pre-swizzled source col (u16)
  const u16* Abase = A  + (size_t)(m0g + srow) * 1024 + scol;
  const u16* Bbase = Bw + (size_t)(n0g + srow) * 1024 + scol;

  float bcol[4];
  #pragma unroll
  for (int c = 0; c < 4; c++){
    int gc = n0g + wn*64 + c*16 + lr;
    bcol[c] = (gc < Vn) ? bias[gc] : 0.0f;
  }

  f32x4 acc[8][4] = {};
  bf16x8 a[4][2], b0[2][2], b1[2][2];
  int rsw = (lr & 7) << 3;

  auto stA = [&](int buf, int half, int tile){
    const u16* s = Abase + (size_t)half*128*1024 + tile*64;
    gload16(s,           &sA[buf][half*128 +      w*8][0]);
    gload16(s + 64*1024, &sA[buf][half*128 + 64 + w*8][0]);
  };
  auto stB = [&](int buf, int half, int tile){
    const u16* s = Bbase + (size_t)half*128*1024 + tile*64;
    gload16(s,           &sB[buf][half*128 +      w*8][0]);
    gload16(s + 64*1024, &sB[buf][half*128 + 64 + w*8][0]);
  };
  auto rdA = [&](int buf, int half){
    #pragma unroll
    for (int i = 0; i < 4; i++)
      #pragma unroll
      for (int kk = 0; kk < 2; kk++)
        a[i][kk] = *(const bf16x8*)&sA[buf][wm*128 + half*64 + i*16 + lr][(kk*32 + lg*8) ^ rsw];
  };
  auto rdB = [&](int buf, int half, bf16x8 (&bb)[2][2]){
    #pragma unroll
    for (int j = 0; j < 2; j++)
      #pragma unroll
      for (int kk = 0; kk < 2; kk++)
        bb[j][kk] = *(const bf16x8*)&sB[buf][wn*64 + half*32 + j*16 + lr][(kk*32 + lg*8) ^ rsw];
  };
  auto MF = [&](int mb, int nb, bf16x8 (&bb)[2][2]){
    __builtin_amdgcn_s_setprio(1);
    #pragma unroll
    for (int kk = 0; kk < 2; kk++)
      #pragma unroll
      for (int i = 0; i < 4; i++)
        #pragma unroll
        for (int j = 0; j < 2; j++)
          acc[mb+i][nb+j] = __builtin_amdgcn_mfma_f32_16x16x32_bf16(a[i][kk], bb[j][kk], acc[mb+i][nb+j], 0, 0, 0);
    __builtin_amdgcn_s_setprio(0);
  };
  auto STQ = [&](int mb, int nb){
    #pragma unroll
    for (int mi = 0; mi < 4; mi++){
      int gr = m0g + wm*128 + (mb+mi)*16 + lg*4;
      #pragma unroll
      for (int j = 0; j < 2; j++){
        int gc = n0g + wn*64 + (nb+j)*16 + lr;
        if (gc < Vn){
          float bb = bcol[nb+j];
          #pragma unroll
          for (int r = 0; r < 4; r++)
            out[(size_t)(gr + r) * Vn + gc] = acc[mb+mi][nb+j][r] + bb;
        }
      }
    }
  };

  // prologue: tile0 full + tile1 B-halves; wait tile0 landed (allow t1.B in flight)
  stA(0,0,0); stA(0,1,0); stB(0,0,0); stB(0,1,0);
  stB(1,0,1); stB(1,1,1);
  VMC4();
  BARR();

  for (int it = 0; it < 7; ++it){
    int T = it * 2;
    // ---- tile T (buf0) ----
    rdA(0,0); rdB(0,0,b0);                 // P1
    stA(1,0,T+1);
    BARR(); LGK0(); MF(0,0,b0); BARR();
    rdB(0,1,b1);                           // P2
    stA(1,1,T+1);
    BARR(); LGK0(); MF(0,2,b1); BARR();
    rdA(0,1);                              // P3
    stB(0,0,T+2);
    BARR(); LGK0(); MF(4,2,b1); BARR();
    stB(0,1,T+2);                          // P4
    BARR(); MF(4,0,b0); VMC4(); BARR();
    // ---- tile T+1 (buf1) ----
    rdA(1,0); rdB(1,0,b0);                 // P5
    stA(0,0,T+2);
    BARR(); LGK0(); MF(0,0,b0); BARR();
    rdB(1,1,b1);                           // P6
    stA(0,1,T+2);
    BARR(); LGK0(); MF(0,2,b1); BARR();
    rdA(1,1);                              // P7
    stB(1,0,T+3);
    BARR(); LGK0(); MF(4,2,b1); BARR();
    stB(1,1,T+3);                          // P8
    BARR(); MF(4,0,b0); VMC4(); BARR();
  }

  // ---- peeled it=7: tiles 14 (buf0) and 15 (buf1); stores interleaved ----
  rdA(0,0); rdB(0,0,b0);                   // P1
  stA(1,0,15);
  BARR(); LGK0(); MF(0,0,b0); BARR();
  rdB(0,1,b1);                             // P2
  stA(1,1,15);
  BARR(); LGK0(); MF(0,2,b1); BARR();
  rdA(0,1);                                // P3 (no staging left)
  BARR(); LGK0(); MF(4,2,b1); BARR();
  BARR(); MF(4,0,b0); VMC0(); BARR();      // P4: drain all staging (tile 15 A+B)
  rdA(1,0); rdB(1,0,b0);                   // P5
  BARR(); LGK0(); MF(0,0,b0); STQ(0,0); BARR();
  rdB(1,1,b1);                             // P6
  BARR(); LGK0(); MF(0,2,b1); STQ(0,2); BARR();
  rdA(1,1);                                // P7
  BARR(); LGK0(); MF(4,2,b1); STQ(4,2); BARR();
  BARR(); MF(4,0,b0); STQ(4,0);            // P8: final quadrant stores, wave drains
}

// ---------------- MFMA fused causal attention (dbuf K/V, T14 staging, T13 defer-max) ----------------
__global__ __launch_bounds__(256) void attn_mfma(const u16* __restrict__ qkv,
                                                 const u16* __restrict__ vT,
                                                 float* __restrict__ x){
  int bid = blockIdx.x;
  int bh = bid & 31;
  int j = bid >> 5;
  int qt = (j < 8) ? (15 - j) : (j - 8);
  int b = bh >> 4, h_ = bh & 15;
  int t = threadIdx.x;
  int w = t >> 6, lane = t & 63;
  int lr = lane & 15, lg = lane >> 4;

  __shared__ u16 sK [2][64][72];
  __shared__ u16 sVt[2][64][72];
  __shared__ u16 sP [64][72];

  const u16* qbase = qkv + ((size_t)(b*Tn + qt*64 + w*16 + lr)) * 3*Dm + h_*64 + lg*8;
  bf16x8 qf[2];
  #pragma unroll
  for (int i = 0; i < 2; i++){
    u16x8 raw = *(const u16x8*)(qbase + i * 32);
    #pragma unroll
    for (int u = 0; u < 8; u++) qf[i][u] = (__bf16)(bf2f(raw[u]) * 0.03125f);
  }

  f32x4 o_[4] = {};
  float m_[4], l_[4];
  #pragma unroll
  for (int r = 0; r < 4; r++){ m_[r] = -INFINITY; l_[r] = 0.0f; }

  int sr = t >> 2, scc = (t & 3) * 16;
  const u16* kbase = qkv + ((size_t)(b*Tn + sr)) * 3*Dm + Dm + h_*64 + scc;
  const u16* vbase = vT + ((size_t)(bh*64 + sr)) * Tn + scc;
  int4 kr0, kr1, vr0, vr1;

  kr0 = *(const int4*)(kbase);     kr1 = *(const int4*)(kbase + 8);
  vr0 = *(const int4*)(vbase);     vr1 = *(const int4*)(vbase + 8);
  *(int4*)&sK [0][sr][scc]     = kr0;  *(int4*)&sK [0][sr][scc + 8] = kr1;
  *(int4*)&sVt[0][sr][scc]     = vr0;  *(int4*)&sVt[0][sr][scc + 8] = vr1;

  for (int kt = 0; kt <= qt; kt++){
    int cur = kt & 1;
    if (kt < qt){                  // T14: issue next tile's loads before compute
      const u16* kb = kbase + (size_t)(kt + 1) * 64 * 3 * Dm;
      const u16* vb = vbase + (kt + 1) * 64;
      kr0 = *(const int4*)(kb);    kr1 = *(const int4*)(kb + 8);
      vr0 = *(const int4*)(vb);    vr1 = *(const int4*)(vb + 8);
    }
    __syncthreads();

    f32x4 s[4] = {};
    __builtin_amdgcn_s_setprio(1);
    #pragma unroll
    for (int kf = 0; kf < 2; kf++){
      #pragma unroll
      for (int nf = 0; nf < 4; nf++){
        bf16x8 kfrag = *(const bf16x8*)&sK[cur][nf*16 + lr][kf*32 + lg*8];
        s[nf] = __builtin_amdgcn_mfma_f32_16x16x32_bf16(qf[kf], kfrag, s[nf], 0, 0, 0);
      }
    }
    __builtin_amdgcn_s_setprio(0);

    bool lastt = (kt == qt);
    float tmax[4] = {-INFINITY, -INFINITY, -INFINITY, -INFINITY};
    #pragma unroll
    for (int nf = 0; nf < 4; nf++)
      #pragma unroll
      for (int r = 0; r < 4; r++){
        float v = s[nf][r];
        if (lastt){
          int kkg = nf*16 + lr, qg = w*16 + lg*4 + r;
          if (kkg > qg) v = -INFINITY;
        }
        s[nf][r] = v;
        tmax[r] = fmaxf(tmax[r], v);
      }
    #pragma unroll
    for (int r = 0; r < 4; r++){
      tmax[r] = fmaxf(tmax[r], __shfl_xor(tmax[r], 1));
      tmax[r] = fmaxf(tmax[r], __shfl_xor(tmax[r], 2));
      tmax[r] = fmaxf(tmax[r], __shfl_xor(tmax[r], 4));
      tmax[r] = fmaxf(tmax[r], __shfl_xor(tmax[r], 8));
    }
    // T13 defer-max: skip rescale while per-row growth <= 8 (P bounded by e^8, f32-safe)
    bool need = false;
    #pragma unroll
    for (int r = 0; r < 4; r++) need = need || (tmax[r] > m_[r] + 8.0f);
    if (__any(need)){
      #pragma unroll
      for (int r = 0; r < 4; r++){
        float nm = fmaxf(m_[r], tmax[r]);
        float resc = __expf(m_[r] - nm);
        m_[r] = nm;
        l_[r] *= resc;
        #pragma unroll
        for (int df = 0; df < 4; df++) o_[df][r] *= resc;
      }
    }
    float psum[4] = {0.f, 0.f, 0.f, 0.f};
    #pragma unroll
    for (int nf = 0; nf < 4; nf++)
      #pragma unroll
      for (int r = 0; r < 4; r++){
        float pv = __expf(s[nf][r] - m_[r]);
        s[nf][r] = pv;
        psum[r] += pv;
      }
    #pragma unroll
    for (int r = 0; r < 4; r++){
      psum[r] += __shfl_xor(psum[r], 1);
      psum[r] += __shfl_xor(psum[r], 2);
      psum[r] += __shfl_xor(psum[r], 4);
      psum[r] += __shfl_xor(psum[r], 8);
      l_[r] += psum[r];
    }

    #pragma unroll
    for (int nf = 0; nf < 4; nf++)
      #pragma unroll
      for (int r = 0; r < 4; r++)
        sP[w*16 + lg*4 + r][nf*16 + lr] = f2bf(s[nf][r]);

    __builtin_amdgcn_s_setprio(1);
    #pragma unroll
    for (int kf = 0; kf < 2; kf++){
      bf16x8 pfrag = *(const bf16x8*)&sP[w*16 + lr][kf*32 + lg*8];
      #pragma unroll
      for (int df = 0; df < 4; df++){
        bf16x8 vfrag = *(const bf16x8*)&sVt[cur][df*16 + lr][kf*32 + lg*8];
        o_[df] = __builtin_amdgcn_mfma_f32_16x16x32_bf16(pfrag, vfrag, o_[df], 0, 0, 0);
      }
    }
    __builtin_amdgcn_s_setprio(0);

    if (kt < qt){                  // write-late: land next tile in the other buffer
      int nxt = cur ^ 1;
      *(int4*)&sK [nxt][sr][scc]     = kr0;  *(int4*)&sK [nxt][sr][scc + 8] = kr1;
      *(int4*)&sVt[nxt][sr][scc]     = vr0;  *(int4*)&sVt[nxt][sr][scc + 8] = vr1;
    }
  }

  float inv[4];
  #pragma unroll
  for (int r = 0; r < 4; r++) inv[r] = 1.0f / l_[r];
  #pragma unroll
  for (int df = 0; df < 4; df++)
    #pragma unroll
    for (int r = 0; r < 4; r++){
      float* xr = x + ((size_t)(b*Tn + qt*64 + w*16 + lg*4 + r)) * Dm + h_*64 + df*16 + lr;
      *xr += o_[df][r] * inv[r];
    }
}

// ---------------- host orchestration ----------------
extern "C" void kernel_launch(void* const* d_in, const int* in_sizes, int n_in,
                              void* d_out, int out_size, void* d_ws, size_t ws_size,
                              hipStream_t stream){
  const int*   idx   = (const int*)  d_in[0];
  const float* emb   = (const float*)d_in[1];
  const float* pos   = (const float*)d_in[2];
  const float* ln1w  = (const float*)d_in[3];
  const float* ln1b  = (const float*)d_in[4];
  const float* qkvw  = (const float*)d_in[5];
  const float* qkvb  = (const float*)d_in[6];
  const float* ln2w  = (const float*)d_in[7];
  const float* ln2b  = (const float*)d_in[8];
  const float* fc1w  = (const float*)d_in[9];
  const float* fc1b  = (const float*)d_in[10];
  const float* fc2w  = (const float*)d_in[11];
  const float* fc2b  = (const float*)d_in[12];
  const float* lnfw  = (const float*)d_in[13];
  const float* lnfb  = (const float*)d_in[14];
  const float* headw = (const float*)d_in[15];
  const float* headb = (const float*)d_in[16];
  float* out = (float*)d_out;

  const size_t MB = 1u << 20;
  char* ws = (char*)d_ws;
  float* x   = (float*)(ws);                       // 8 MB  [2048][1024] f32
  u16*   h   = (u16*)  (ws + 8*MB);                // 4 MB  [2048][1024] bf16
  u16*   qkv = (u16*)  (ws + 12*MB);               // 12 MB [2048][3072] bf16
  u16*   f1  = (u16*)  (ws + 24*MB);               // 16 MB [2048][4096] bf16

  bool mega    = ws_size >= 320*MB;
  bool bighead = ws_size >= 116*MB;

  u16 *vT, *Bt = nullptr, *BtF = nullptr, *Wq = nullptr, *W1 = nullptr, *W2 = nullptr, *Wh = nullptr;
  if (mega){
    vT = (u16*)(ws + 40*MB);                       // 4 MB
    Wq = (u16*)(ws + 44*MB);                       // 48 MB  (8 x 3072x1024)
    W1 = (u16*)(ws + 92*MB);                       // 64 MB  (8 x 4096x1024)
    W2 = (u16*)(ws + 156*MB);                      // 64 MB  (8 x 1024x4096)
    Wh = (u16*)(ws + 220*MB);                      // 98.5 MiB (50432x1024)
  } else {
    Bt  = (u16*)(ws + 40*MB);
    vT  = (u16*)(ws + 48*MB);
    BtF = (u16*)(ws + 12*MB);
  }

  if (mega)
    mega_transpose<<<35136, 256, 0, stream>>>(qkvw, fc1w, fc2w, headw, Wq, W1, W2, Wh);

  embed_kernel<<<NTOK, 256, 0, stream>>>(idx, emb, pos, x);

  for (int l = 0; l < Ln; l++){
    const u16* Bq = mega ? Wq + (size_t)l*3072*Dm : Bt;
    const u16* B1 = mega ? W1 + (size_t)l*Fm*Dm   : Bt;
    const u16* B2 = mega ? W2 + (size_t)l*Dm*Fm   : Bt;
    // --- attention block ---
    ln_kernel<<<NTOK, 256, 0, stream>>>(x, ln1w + l*Dm, ln1b + l*Dm, h);
    if (!mega) transpose_w<<<dim3(3072/64, Dm/64), 256, 0, stream>>>(qkvw + (size_t)l*Dm*3072, Bt, 3072, Dm, 0);
    gemm_kernel<0, 64,128,1,4,false><<<dim3(3072/128, NTOK/64), 256, 0, stream>>>(h, Bq, qkvb + l*3072, qkv, nullptr, vT, Dm, 3072, 0);
    attn_mfma<<<512, 256, 0, stream>>>(qkv, vT, x);
    // --- MLP block ---
    ln_kernel<<<NTOK, 256, 0, stream>>>(x, ln2w + l*Dm, ln2b + l*Dm, h);
    if (!mega) transpose_w<<<dim3(Fm/64, Dm/64), 256, 0, stream>>>(fc1w + (size_t)l*Dm*Fm, Bt, Fm, Dm, 0);
    gemm_kernel<1,128,128,2,2,false><<<dim3(Fm/128, NTOK/128), 256, 0, stream>>>(h, B1, fc1b + l*Fm, f1, nullptr, nullptr, Dm, Fm, 0);
    if (!mega) transpose_w<<<dim3(Dm/64, Fm/64), 256, 0, stream>>>(fc2w + (size_t)l*Fm*Dm, Bt, Dm, Fm, 0);
    gemm_kernel<2, 64,64,2,2,false><<<dim3(Dm/64, NTOK/64), 256, 0, stream>>>(f1, B2, fc2b + l*Dm, nullptr, x, nullptr, Fm, Dm, 0);
  }

  ln_kernel<<<NTOK, 256, 0, stream>>>(x, lnfw, lnfb, h);

  if (mega){
    head_gemm_8ph<<<1576, 512, 0, stream>>>(h, Wh, headb, out);    // 8 m x 197 n tiles
  } else if (bighead){
    transpose_w<<<dim3(786, Dm/64), 256, 0, stream>>>(headw, BtF, Vn, Dm, 0);
    gemm_kernel<3,128,128,2,2,true><<<6288, 256, 0, stream>>>(h, BtF, headb, out, nullptr, nullptr, Dm, Vn, 0);
  } else {
    const int CHUNK = 4096;
    for (int c0 = 0; c0 < Vn; c0 += CHUNK){
      int W = Vn - c0; if (W > CHUNK) W = CHUNK;
      int ngx = (W + 127) / 128;
      transpose_w<<<dim3(ngx * 2, Dm/64), 256, 0, stream>>>(headw, Bt, Vn, Dm, c0);
      gemm_kernel<3,128,128,2,2,false><<<dim3(ngx, NTOK/128), 256, 0, stream>>>(h, Bt, headb, out, nullptr, nullptr, Dm, Vn, c0);
    }
  }
}

// Round 12
// 1733.719 us; speedup vs baseline: 1.3543x; 1.0330x over previous
//
#include <hip/hip_runtime.h>
#include <math.h>

#define Ln 8
#define Bn 2
#define Tn 1024
#define Dm 1024
#define Hn 16
#define Fm 4096
#define Vn 50257
#define NTOK 2048   // B*T

typedef unsigned short u16;
typedef u16   u16x8  __attribute__((ext_vector_type(8)));
typedef __bf16 bf16x8 __attribute__((ext_vector_type(8)));
typedef float f32x4  __attribute__((ext_vector_type(4)));

__device__ __forceinline__ u16 f2bf(float f){
  unsigned u = __builtin_bit_cast(unsigned, f);
  u += 0x7FFFu + ((u >> 16) & 1u);            // RNE
  return (u16)(u >> 16);
}
__device__ __forceinline__ float bf2f(u16 s){
  return __builtin_bit_cast(float, ((unsigned)s) << 16);
}
__device__ __forceinline__ float gelu_f(float v){
  return 0.5f * v * (1.0f + erff(v * 0.70710678118654752440f));
}
__device__ __forceinline__ void gload16(const void* g, void* l){
  __builtin_amdgcn_global_load_lds(
      (const __attribute__((address_space(1))) void*)g,
      (__attribute__((address_space(3))) void*)l, 16, 0, 0);
}

// ---------------- embedding ----------------
__global__ __launch_bounds__(256) void embed_kernel(const int* __restrict__ idx,
                                                    const float* __restrict__ emb,
                                                    const float* __restrict__ pos,
                                                    float* __restrict__ x){
  int row = blockIdx.x;
  int t = row & (Tn - 1);
  int id = idx[row];
  const float4* e = (const float4*)(emb + (size_t)id * Dm);
  const float4* p = (const float4*)(pos + (size_t)t * Dm);
  float4* o = (float4*)(x + (size_t)row * Dm);
  int i = threadIdx.x;
  float4 a = e[i], b = p[i];
  o[i] = make_float4(a.x + b.x, a.y + b.y, a.z + b.z, a.w + b.w);
}

// ---------------- layernorm, wave-per-row (4 rows/block, no LDS, no barrier) ----------------
__global__ __launch_bounds__(256) void ln_kernel(const float* __restrict__ xin,
                                                 const float* __restrict__ w,
                                                 const float* __restrict__ bb,
                                                 u16* __restrict__ out){
  int row = blockIdx.x * 4 + (threadIdx.x >> 6);
  int lane = threadIdx.x & 63;
  const float4* xr = (const float4*)(xin + (size_t)row * Dm);
  float4 v[4];
  float s = 0.0f, s2 = 0.0f;
  #pragma unroll
  for (int i = 0; i < 4; i++){
    v[i] = xr[lane + i * 64];
    s  += v[i].x + v[i].y + v[i].z + v[i].w;
    s2 += v[i].x*v[i].x + v[i].y*v[i].y + v[i].z*v[i].z + v[i].w*v[i].w;
  }
  #pragma unroll
  for (int off = 1; off < 64; off <<= 1){
    s  += __shfl_xor(s, off);
    s2 += __shfl_xor(s2, off);
  }
  float mean = s * (1.0f / Dm);
  float var  = s2 * (1.0f / Dm) - mean * mean;
  float rs = rsqrtf(var + 1e-5f);
  #pragma unroll
  for (int i = 0; i < 4; i++){
    int c = lane + i * 64;
    float4 wv = ((const float4*)w)[c];
    float4 bv = ((const float4*)bb)[c];
    u16 o4[4];
    o4[0] = f2bf((v[i].x - mean) * rs * wv.x + bv.x);
    o4[1] = f2bf((v[i].y - mean) * rs * wv.y + bv.y);
    o4[2] = f2bf((v[i].z - mean) * rs * wv.z + bv.z);
    o4[3] = f2bf((v[i].w - mean) * rs * wv.w + bv.w);
    *(uint2*)(out + (size_t)row * Dm + c * 4) = *(uint2*)o4;
  }
}

// ---------------- transpose tile: f32 src[k][srcCol+*] -> bf16 dst[dstRow+*][k] ----------------
__device__ __forceinline__ void trans_tile(const float* __restrict__ src,
                                           u16* __restrict__ dst,
                                           int N, int K, int srcCol, int dstRow, int k0){
  __shared__ float tile[64][66];
  int t = threadIdx.x;
  int rr = t >> 4, nc = (t & 15) * 4;
  #pragma unroll
  for (int u = 0; u < 4; u++){
    int kk = rr + u * 16;
    int gn = srcCol + nc;
    const float* sp = src + (size_t)(k0 + kk) * N;
    float4 v;
    if (gn + 3 < N) v = *(const float4*)(sp + gn);
    else {
      v.x = (gn     < N) ? sp[gn]     : 0.0f;
      v.y = (gn + 1 < N) ? sp[gn + 1] : 0.0f;
      v.z = (gn + 2 < N) ? sp[gn + 2] : 0.0f;
      v.w = (gn + 3 < N) ? sp[gn + 3] : 0.0f;
    }
    tile[kk][nc]     = v.x;
    tile[kk][nc + 1] = v.y;
    tile[kk][nc + 2] = v.z;
    tile[kk][nc + 3] = v.w;
  }
  __syncthreads();
  int np = t >> 2, c = t & 3;
  u16* dp = dst + (size_t)(dstRow + np) * K + k0;
  u16 pk[8];
  #pragma unroll
  for (int j = 0; j < 8; j++) pk[j] = f2bf(tile[c*8 + j][np]);
  *(int4*)(dp + c*8) = *(int4*)pk;
  #pragma unroll
  for (int j = 0; j < 8; j++) pk[j] = f2bf(tile[32 + c*8 + j][np]);
  *(int4*)(dp + 32 + c*8) = *(int4*)pk;
}

__global__ __launch_bounds__(256) void transpose_w(const float* __restrict__ Bw,
                                                   u16* __restrict__ Bt,
                                                   int N, int K, int c0){
  int n0 = blockIdx.x * 64, k0 = blockIdx.y * 64;
  trans_tile(Bw, Bt, N, K, c0 + n0, n0, k0);
}

// all layer weights + head in ONE dispatch.
__global__ __launch_bounds__(256) void mega_transpose(const float* __restrict__ qkvw,
                                                      const float* __restrict__ fc1w,
                                                      const float* __restrict__ fc2w,
                                                      const float* __restrict__ headw,
                                                      u16* __restrict__ Wq,
                                                      u16* __restrict__ W1,
                                                      u16* __restrict__ W2,
                                                      u16* __restrict__ Wh){
  int id = blockIdx.x;
  const float* src; u16* dst; int N, K, n0, k0;
  if (id < 6144){
    int l = id / 768, r = id % 768;
    n0 = (r % 48) * 64; k0 = (r / 48) * 64;
    src = qkvw + (size_t)l * Dm * 3072; dst = Wq + (size_t)l * 3072 * Dm;
    N = 3072; K = Dm;
  } else if (id < 14336){
    int id2 = id - 6144;
    int l = id2 / 1024, r = id2 % 1024;
    n0 = (r % 64) * 64; k0 = (r / 64) * 64;
    src = fc1w + (size_t)l * Dm * Fm; dst = W1 + (size_t)l * Fm * Dm;
    N = Fm; K = Dm;
  } else if (id < 22528){
    int id2 = id - 14336;
    int l = id2 / 1024, r = id2 % 1024;
    n0 = (r % 16) * 64; k0 = (r / 16) * 64;
    src = fc2w + (size_t)l * Fm * Dm; dst = W2 + (size_t)l * Dm * Fm;
    N = Dm; K = Fm;
  } else {
    int id2 = id - 22528;
    n0 = (id2 % 788) * 64; k0 = (id2 / 788) * 64;   // 50432 rows, zero-filled past 50257
    src = headw; dst = Wh;
    N = Vn; K = Dm;
  }
  trans_tile(src, dst, N, K, n0, n0, k0);
}

// ---------------- generic 2-phase GEMM (layer GEMMs + fallback) ----------------
template<int MODE, int BMt, int BNt, int WM, int WN, bool SWZ>
__global__ __launch_bounds__(256) void gemm_kernel(const u16* __restrict__ A,
                                                   const u16* __restrict__ Bt,
                                                   const float* __restrict__ bias,
                                                   void* __restrict__ outp,
                                                   float* __restrict__ resid,
                                                   u16* __restrict__ vT,
                                                   int K, int Nout, int c0){
  constexpr int MR = BMt / (WM * 16);
  constexpr int NR = BNt / (WN * 16);
  __shared__ u16 sA[BMt][64];
  __shared__ u16 sB[BNt][64];
  int t = threadIdx.x;
  int lane = t & 63, w = t >> 6;
  int wm = w / WN, wn = w % WN;
  int lr = lane & 15, lg = lane >> 4;
  int m0, n0;
  if (SWZ){
    int orig = blockIdx.x;
    int q = gridDim.x >> 3;
    int wg = (orig & 7) * q + (orig >> 3);
    m0 = (wg & 15) * BMt;
    n0 = (wg >> 4) * BNt;
  } else {
    m0 = blockIdx.y * BMt; n0 = blockIdx.x * BNt;
  }

  f32x4 acc[MR][NR] = {};

  int srow = lane >> 3;
  int gcs = ((lane & 7) ^ (lane >> 3)) * 8;        // pre-swizzled global k-col (u16)
  int cswz = (lr & 7) << 3;                        // read-side swizzle

  for (int k0 = 0; k0 < K; k0 += 64){
    __syncthreads();
    #pragma unroll
    for (int i = 0; i < BMt/32; i++){
      int rbase = i*32 + w*8;
      gload16(A + (size_t)(m0 + rbase + srow) * K + k0 + gcs, (char*)&sA[rbase][0]);
    }
    #pragma unroll
    for (int i = 0; i < BNt/32; i++){
      int rbase = i*32 + w*8;
      gload16(Bt + (size_t)(n0 + rbase + srow) * K + k0 + gcs, (char*)&sB[rbase][0]);
    }
    __syncthreads();
    #pragma unroll
    for (int kk = 0; kk < 2; kk++){
      bf16x8 af[MR], bfr[NR];
      #pragma unroll
      for (int i = 0; i < MR; i++) af[i]  = *(const bf16x8*)&sA[wm*(MR*16) + i*16 + lr][(kk*32 + lg*8) ^ cswz];
      #pragma unroll
      for (int j = 0; j < NR; j++) bfr[j] = *(const bf16x8*)&sB[wn*(NR*16) + j*16 + lr][(kk*32 + lg*8) ^ cswz];
      #pragma unroll
      for (int i = 0; i < MR; i++)
        #pragma unroll
        for (int j = 0; j < NR; j++)
          acc[i][j] = __builtin_amdgcn_mfma_f32_16x16x32_bf16(af[i], bfr[j], acc[i][j], 0, 0, 0);
    }
  }

  #pragma unroll
  for (int i = 0; i < MR; i++){
    int gr0 = m0 + wm*(MR*16) + i*16 + lg*4;
    #pragma unroll
    for (int j = 0; j < NR; j++){
      int gc = c0 + n0 + wn*(NR*16) + j*16 + lr;
      if (MODE == 3 && gc >= Nout) continue;
      float bb = bias[gc];
      if (MODE == 0 && gc >= 2048){
        int hh = (gc - 2048) >> 6, dd = (gc - 2048) & 63;
        int b_ = gr0 >> 10, tt = gr0 & 1023;
        u16 pk[4];
        #pragma unroll
        for (int r = 0; r < 4; r++) pk[r] = f2bf(acc[i][j][r] + bb);
        *(uint2*)&vT[((size_t)((b_*Hn + hh)*64 + dd))*Tn + tt] = *(uint2*)pk;
        continue;
      }
      #pragma unroll
      for (int r = 0; r < 4; r++){
        float v = acc[i][j][r] + bb;
        size_t oi = (size_t)(gr0 + r) * Nout + gc;
        if (MODE == 0)      ((u16*)outp)[oi] = f2bf(v);
        else if (MODE == 1) ((u16*)outp)[oi] = f2bf(gelu_f(v));
        else if (MODE == 2) resid[oi] = resid[oi] + gelu_f(v);
        else                ((float*)outp)[oi] = v;
      }
    }
  }
}

// ---------------- 8-phase 256x256 head GEMM (r8 version — best measured, exact) ----------------
#define BARR() __builtin_amdgcn_s_barrier()
#define LGK0() asm volatile("s_waitcnt lgkmcnt(0)" ::: "memory")
#define VMC4() asm volatile("s_waitcnt vmcnt(4)" ::: "memory")

__global__ __launch_bounds__(512) void head_gemm_8ph(const u16* __restrict__ A,
                                                     const u16* __restrict__ Bw,
                                                     const float* __restrict__ bias,
                                                     float* __restrict__ out){
  __shared__ u16 sA[2][256][64];
  __shared__ u16 sB[2][256][64];
  int t = threadIdx.x, lane = t & 63, w = t >> 6;
  int wm = w >> 2, wn = w & 3;
  int lr = lane & 15, lg = lane >> 4;
  int orig = blockIdx.x;
  int wg = (orig & 7) * (gridDim.x >> 3) + (orig >> 3);  // XCD-chunked (1576 % 8 == 0)
  int m0g = (wg & 7) << 8;                                // m-fastest: B-panel reuse in-XCD
  int n0g = (wg >> 3) << 8;

  int srow = w*8 + (lane >> 3);
  int scol = ((lane & 7) ^ (lane >> 3)) * 8;     // pre-swizzled source col (u16)
  const u16* Abase = A  + (size_t)(m0g + srow) * 1024 + scol;
  const u16* Bbase = Bw + (size_t)(n0g + srow) * 1024 + scol;

  f32x4 acc[8][4] = {};
  bf16x8 a[4][2], b0[2][2], b1[2][2];
  int rsw = (lr & 7) << 3;

  auto stA = [&](int buf, int half, int tile){
    const u16* s = Abase + (size_t)half*128*1024 + tile*64;
    gload16(s,           &sA[buf][half*128 +      w*8][0]);
    gload16(s + 64*1024, &sA[buf][half*128 + 64 + w*8][0]);
  };
  auto stB = [&](int buf, int half, int tile){
    const u16* s = Bbase + (size_t)half*128*1024 + tile*64;
    gload16(s,           &sB[buf][half*128 +      w*8][0]);
    gload16(s + 64*1024, &sB[buf][half*128 + 64 + w*8][0]);
  };
  auto rdA = [&](int buf, int half){
    #pragma unroll
    for (int i = 0; i < 4; i++)
      #pragma unroll
      for (int kk = 0; kk < 2; kk++)
        a[i][kk] = *(const bf16x8*)&sA[buf][wm*128 + half*64 + i*16 + lr][(kk*32 + lg*8) ^ rsw];
  };
  auto rdB = [&](int buf, int half, bf16x8 (&bb)[2][2]){
    #pragma unroll
    for (int j = 0; j < 2; j++)
      #pragma unroll
      for (int kk = 0; kk < 2; kk++)
        bb[j][kk] = *(const bf16x8*)&sB[buf][wn*64 + half*32 + j*16 + lr][(kk*32 + lg*8) ^ rsw];
  };
  auto MF = [&](int mb, int nb, bf16x8 (&bb)[2][2]){
    __builtin_amdgcn_s_setprio(1);
    #pragma unroll
    for (int kk = 0; kk < 2; kk++)
      #pragma unroll
      for (int i = 0; i < 4; i++)
        #pragma unroll
        for (int j = 0; j < 2; j++)
          acc[mb+i][nb+j] = __builtin_amdgcn_mfma_f32_16x16x32_bf16(a[i][kk], bb[j][kk], acc[mb+i][nb+j], 0, 0, 0);
    __builtin_amdgcn_s_setprio(0);
  };

  // prologue: tile0 full + tile1 B-halves; wait tile0 landed (allow t1.B in flight)
  stA(0,0,0); stA(0,1,0); stB(0,0,0); stB(0,1,0);
  stB(1,0,1); stB(1,1,1);
  VMC4();
  BARR();

  for (int it = 0; it < 8; ++it){
    int T = it * 2;
    // ---- tile T (buf0) ----
    rdA(0,0); rdB(0,0,b0);                 // P1
    stA(1,0,T+1);
    BARR(); LGK0(); MF(0,0,b0); BARR();
    rdB(0,1,b1);                           // P2
    stA(1,1,T+1);
    BARR(); LGK0(); MF(0,2,b1); BARR();
    rdA(0,1);                              // P3
    if (T+2 < 16) stB(0,0,T+2);
    BARR(); LGK0(); MF(4,2,b1); BARR();
    if (T+2 < 16) stB(0,1,T+2);            // P4
    BARR(); MF(4,0,b0); VMC4(); BARR();
    // ---- tile T+1 (buf1) ----
    rdA(1,0); rdB(1,0,b0);                 // P5
    if (T+2 < 16) stA(0,0,T+2);
    BARR(); LGK0(); MF(0,0,b0); BARR();
    rdB(1,1,b1);                           // P6
    if (T+2 < 16) stA(0,1,T+2);
    BARR(); LGK0(); MF(0,2,b1); BARR();
    rdA(1,1);                              // P7
    if (T+3 < 16) stB(1,0,T+3);
    BARR(); LGK0(); MF(4,2,b1); BARR();
    if (T+3 < 16) stB(1,1,T+3);            // P8
    BARR(); MF(4,0,b0); VMC4(); BARR();
  }

  #pragma unroll
  for (int m = 0; m < 8; m++){
    int gr = m0g + wm*128 + m*16 + lg*4;
    #pragma unroll
    for (int n = 0; n < 4; n++){
      int gc = n0g + wn*64 + n*16 + lr;
      if (gc < Vn){
        float bb = bias[gc];
        #pragma unroll
        for (int r = 0; r < 4; r++)
          out[(size_t)(gr + r) * Vn + gc] = acc[m][n][r] + bb;
      }
    }
  }
}

// ---------------- MFMA fused causal attention (dbuf K/V, T14 staging, T13 defer-max) ----------------
__global__ __launch_bounds__(256) void attn_mfma(const u16* __restrict__ qkv,
                                                 const u16* __restrict__ vT,
                                                 float* __restrict__ x){
  int bid = blockIdx.x;
  int bh = bid & 31;
  int j = bid >> 5;
  int qt = (j < 8) ? (15 - j) : (j - 8);
  int b = bh >> 4, h_ = bh & 15;
  int t = threadIdx.x;
  int w = t >> 6, lane = t & 63;
  int lr = lane & 15, lg = lane >> 4;

  __shared__ u16 sK [2][64][72];
  __shared__ u16 sVt[2][64][72];
  __shared__ u16 sP [64][72];

  const u16* qbase = qkv + ((size_t)(b*Tn + qt*64 + w*16 + lr)) * 3*Dm + h_*64 + lg*8;
  bf16x8 qf[2];
  #pragma unroll
  for (int i = 0; i < 2; i++){
    u16x8 raw = *(const u16x8*)(qbase + i * 32);
    #pragma unroll
    for (int u = 0; u < 8; u++) qf[i][u] = (__bf16)(bf2f(raw[u]) * 0.03125f);
  }

  f32x4 o_[4] = {};
  float m_[4], l_[4];
  #pragma unroll
  for (int r = 0; r < 4; r++){ m_[r] = -INFINITY; l_[r] = 0.0f; }

  int sr = t >> 2, scc = (t & 3) * 16;
  const u16* kbase = qkv + ((size_t)(b*Tn + sr)) * 3*Dm + Dm + h_*64 + scc;
  const u16* vbase = vT + ((size_t)(bh*64 + sr)) * Tn + scc;
  int4 kr0, kr1, vr0, vr1;

  kr0 = *(const int4*)(kbase);     kr1 = *(const int4*)(kbase + 8);
  vr0 = *(const int4*)(vbase);     vr1 = *(const int4*)(vbase + 8);
  *(int4*)&sK [0][sr][scc]     = kr0;  *(int4*)&sK [0][sr][scc + 8] = kr1;
  *(int4*)&sVt[0][sr][scc]     = vr0;  *(int4*)&sVt[0][sr][scc + 8] = vr1;

  for (int kt = 0; kt <= qt; kt++){
    int cur = kt & 1;
    if (kt < qt){                  // T14: issue next tile's loads before compute
      const u16* kb = kbase + (size_t)(kt + 1) * 64 * 3 * Dm;
      const u16* vb = vbase + (kt + 1) * 64;
      kr0 = *(const int4*)(kb);    kr1 = *(const int4*)(kb + 8);
      vr0 = *(const int4*)(vb);    vr1 = *(const int4*)(vb + 8);
    }
    __syncthreads();

    f32x4 s[4] = {};
    __builtin_amdgcn_s_setprio(1);
    #pragma unroll
    for (int kf = 0; kf < 2; kf++){
      #pragma unroll
      for (int nf = 0; nf < 4; nf++){
        bf16x8 kfrag = *(const bf16x8*)&sK[cur][nf*16 + lr][kf*32 + lg*8];
        s[nf] = __builtin_amdgcn_mfma_f32_16x16x32_bf16(qf[kf], kfrag, s[nf], 0, 0, 0);
      }
    }
    __builtin_amdgcn_s_setprio(0);

    bool lastt = (kt == qt);
    float tmax[4] = {-INFINITY, -INFINITY, -INFINITY, -INFINITY};
    #pragma unroll
    for (int nf = 0; nf < 4; nf++)
      #pragma unroll
      for (int r = 0; r < 4; r++){
        float v = s[nf][r];
        if (lastt){
          int kkg = nf*16 + lr, qg = w*16 + lg*4 + r;
          if (kkg > qg) v = -INFINITY;
        }
        s[nf][r] = v;
        tmax[r] = fmaxf(tmax[r], v);
      }
    #pragma unroll
    for (int r = 0; r < 4; r++){
      tmax[r] = fmaxf(tmax[r], __shfl_xor(tmax[r], 1));
      tmax[r] = fmaxf(tmax[r], __shfl_xor(tmax[r], 2));
      tmax[r] = fmaxf(tmax[r], __shfl_xor(tmax[r], 4));
      tmax[r] = fmaxf(tmax[r], __shfl_xor(tmax[r], 8));
    }
    // T13 defer-max: skip rescale while per-row growth <= 8 (P bounded by e^8, f32-safe)
    bool need = false;
    #pragma unroll
    for (int r = 0; r < 4; r++) need = need || (tmax[r] > m_[r] + 8.0f);
    if (__any(need)){
      #pragma unroll
      for (int r = 0; r < 4; r++){
        float nm = fmaxf(m_[r], tmax[r]);
        float resc = __expf(m_[r] - nm);
        m_[r] = nm;
        l_[r] *= resc;
        #pragma unroll
        for (int df = 0; df < 4; df++) o_[df][r] *= resc;
      }
    }
    float psum[4] = {0.f, 0.f, 0.f, 0.f};
    #pragma unroll
    for (int nf = 0; nf < 4; nf++)
      #pragma unroll
      for (int r = 0; r < 4; r++){
        float pv = __expf(s[nf][r] - m_[r]);
        s[nf][r] = pv;
        psum[r] += pv;
      }
    #pragma unroll
    for (int r = 0; r < 4; r++){
      psum[r] += __shfl_xor(psum[r], 1);
      psum[r] += __shfl_xor(psum[r], 2);
      psum[r] += __shfl_xor(psum[r], 4);
      psum[r] += __shfl_xor(psum[r], 8);
      l_[r] += psum[r];
    }

    #pragma unroll
    for (int nf = 0; nf < 4; nf++)
      #pragma unroll
      for (int r = 0; r < 4; r++)
        sP[w*16 + lg*4 + r][nf*16 + lr] = f2bf(s[nf][r]);

    __builtin_amdgcn_s_setprio(1);
    #pragma unroll
    for (int kf = 0; kf < 2; kf++){
      bf16x8 pfrag = *(const bf16x8*)&sP[w*16 + lr][kf*32 + lg*8];
      #pragma unroll
      for (int df = 0; df < 4; df++){
        bf16x8 vfrag = *(const bf16x8*)&sVt[cur][df*16 + lr][kf*32 + lg*8];
        o_[df] = __builtin_amdgcn_mfma_f32_16x16x32_bf16(pfrag, vfrag, o_[df], 0, 0, 0);
      }
    }
    __builtin_amdgcn_s_setprio(0);

    if (kt < qt){                  // write-late: land next tile in the other buffer
      int nxt = cur ^ 1;
      *(int4*)&sK [nxt][sr][scc]     = kr0;  *(int4*)&sK [nxt][sr][scc + 8] = kr1;
      *(int4*)&sVt[nxt][sr][scc]     = vr0;  *(int4*)&sVt[nxt][sr][scc + 8] = vr1;
    }
  }

  float inv[4];
  #pragma unroll
  for (int r = 0; r < 4; r++) inv[r] = 1.0f / l_[r];
  #pragma unroll
  for (int df = 0; df < 4; df++)
    #pragma unroll
    for (int r = 0; r < 4; r++){
      float* xr = x + ((size_t)(b*Tn + qt*64 + w*16 + lg*4 + r)) * Dm + h_*64 + df*16 + lr;
      *xr += o_[df][r] * inv[r];
    }
}

// ---------------- host orchestration ----------------
extern "C" void kernel_launch(void* const* d_in, const int* in_sizes, int n_in,
                              void* d_out, int out_size, void* d_ws, size_t ws_size,
                              hipStream_t stream){
  const int*   idx   = (const int*)  d_in[0];
  const float* emb   = (const float*)d_in[1];
  const float* pos   = (const float*)d_in[2];
  const float* ln1w  = (const float*)d_in[3];
  const float* ln1b  = (const float*)d_in[4];
  const float* qkvw  = (const float*)d_in[5];
  const float* qkvb  = (const float*)d_in[6];
  const float* ln2w  = (const float*)d_in[7];
  const float* ln2b  = (const float*)d_in[8];
  const float* fc1w  = (const float*)d_in[9];
  const float* fc1b  = (const float*)d_in[10];
  const float* fc2w  = (const float*)d_in[11];
  const float* fc2b  = (const float*)d_in[12];
  const float* lnfw  = (const float*)d_in[13];
  const float* lnfb  = (const float*)d_in[14];
  const float* headw = (const float*)d_in[15];
  const float* headb = (const float*)d_in[16];
  float* out = (float*)d_out;

  const size_t MB = 1u << 20;
  char* ws = (char*)d_ws;
  float* x   = (float*)(ws);                       // 8 MB  [2048][1024] f32
  u16*   h   = (u16*)  (ws + 8*MB);                // 4 MB  [2048][1024] bf16
  u16*   qkv = (u16*)  (ws + 12*MB);               // 12 MB [2048][3072] bf16
  u16*   f1  = (u16*)  (ws + 24*MB);               // 16 MB [2048][4096] bf16

  bool mega    = ws_size >= 320*MB;
  bool bighead = ws_size >= 116*MB;

  u16 *vT, *Bt = nullptr, *BtF = nullptr, *Wq = nullptr, *W1 = nullptr, *W2 = nullptr, *Wh = nullptr;
  if (mega){
    vT = (u16*)(ws + 40*MB);                       // 4 MB
    Wq = (u16*)(ws + 44*MB);                       // 48 MB  (8 x 3072x1024)
    W1 = (u16*)(ws + 92*MB);                       // 64 MB  (8 x 4096x1024)
    W2 = (u16*)(ws + 156*MB);                      // 64 MB  (8 x 1024x4096)
    Wh = (u16*)(ws + 220*MB);                      // 98.5 MiB (50432x1024)
  } else {
    Bt  = (u16*)(ws + 40*MB);
    vT  = (u16*)(ws + 48*MB);
    BtF = (u16*)(ws + 12*MB);
  }

  if (mega)
    mega_transpose<<<35136, 256, 0, stream>>>(qkvw, fc1w, fc2w, headw, Wq, W1, W2, Wh);

  embed_kernel<<<NTOK, 256, 0, stream>>>(idx, emb, pos, x);

  for (int l = 0; l < Ln; l++){
    const u16* Bq = mega ? Wq + (size_t)l*3072*Dm : Bt;
    const u16* B1 = mega ? W1 + (size_t)l*Fm*Dm   : Bt;
    const u16* B2 = mega ? W2 + (size_t)l*Dm*Fm   : Bt;
    // --- attention block ---
    ln_kernel<<<NTOK/4, 256, 0, stream>>>(x, ln1w + l*Dm, ln1b + l*Dm, h);
    if (!mega) transpose_w<<<dim3(3072/64, Dm/64), 256, 0, stream>>>(qkvw + (size_t)l*Dm*3072, Bt, 3072, Dm, 0);
    gemm_kernel<0, 64,128,1,4,false><<<dim3(3072/128, NTOK/64), 256, 0, stream>>>(h, Bq, qkvb + l*3072, qkv, nullptr, vT, Dm, 3072, 0);
    attn_mfma<<<512, 256, 0, stream>>>(qkv, vT, x);
    // --- MLP block ---
    ln_kernel<<<NTOK/4, 256, 0, stream>>>(x, ln2w + l*Dm, ln2b + l*Dm, h);
    if (!mega) transpose_w<<<dim3(Fm/64, Dm/64), 256, 0, stream>>>(fc1w + (size_t)l*Dm*Fm, Bt, Fm, Dm, 0);
    gemm_kernel<1,128,128,2,2,false><<<dim3(Fm/128, NTOK/128), 256, 0, stream>>>(h, B1, fc1b + l*Fm, f1, nullptr, nullptr, Dm, Fm, 0);
    if (!mega) transpose_w<<<dim3(Dm/64, Fm/64), 256, 0, stream>>>(fc2w + (size_t)l*Fm*Dm, Bt, Dm, Fm, 0);
    gemm_kernel<2, 64,64,2,2,false><<<dim3(Dm/64, NTOK/64), 256, 0, stream>>>(f1, B2, fc2b + l*Dm, nullptr, x, nullptr, Fm, Dm, 0);
  }

  ln_kernel<<<NTOK/4, 256, 0, stream>>>(x, lnfw, lnfb, h);

  if (mega){
    head_gemm_8ph<<<1576, 512, 0, stream>>>(h, Wh, headb, out);    // 8 m x 197 n tiles
  } else if (bighead){
    transpose_w<<<dim3(786, Dm/64), 256, 0, stream>>>(headw, BtF, Vn, Dm, 0);
    gemm_kernel<3,128,128,2,2,true><<<6288, 256, 0, stream>>>(h, BtF, headb, out, nullptr, nullptr, Dm, Vn, 0);
  } else {
    const int CHUNK = 4096;
    for (int c0 = 0; c0 < Vn; c0 += CHUNK){
      int W = Vn - c0; if (W > CHUNK) W = CHUNK;
      int ngx = (W + 127) / 128;
      transpose_w<<<dim3(ngx * 2, Dm/64), 256, 0, stream>>>(headw, Bt, Vn, Dm, c0);
      gemm_kernel<3,128,128,2,2,false><<<dim3(ngx, NTOK/128), 256, 0, stream>>>(h, Bt, headb, out, nullptr, nullptr, Dm, Vn, c0);
    }
  }
}